// Round 6
// baseline (2165.893 us; speedup 1.0000x reference)
//
#include <hip/hip_runtime.h>
#include <hip/hip_bf16.h>
#include <math.h>

#define PN   2048
#define PB   16
#define PG   128
#define PM   32
#define PDM  384
#define PDI  768
#define ROWS 2048   // B*G == B*L

typedef unsigned short ushort_t;
typedef unsigned long long ull_t;
typedef __attribute__((ext_vector_type(8))) short bf8;
typedef __attribute__((ext_vector_type(4))) float f4;

__device__ __forceinline__ ushort_t f2bf(float x) {
  unsigned int u = __float_as_uint(x);
  unsigned int r = (u + 0x7FFFu + ((u >> 16) & 1u)) >> 16;
  return (ushort_t)r;
}
__device__ __forceinline__ ull_t umax64(ull_t a, ull_t b) { return a > b ? a : b; }
__device__ __forceinline__ ull_t umin64(ull_t a, ull_t b) { return a < b ? a : b; }

#define GL2L(gp, lp) __builtin_amdgcn_global_load_lds((const __attribute__((address_space(1))) void*)(gp), (__attribute__((address_space(3))) void*)(lp), 16, 0, 0)

// ---------------------------------------------------------------- prep: all weight conversions in ONE launch
#define CV_O1 32768
#define CV_O2 294912
#define CV_O3 491520
#define CV_O4 7569408
#define CV_TOT 11108352
#define DTWT_TOT (12*768*24)
#define XPWT_TOT (12*192*64*4)
#define PREP_TOT (CV_TOT + DTWT_TOT + XPWT_TOT)
__global__ __launch_bounds__(256) void prep_kernel(
    const float* __restrict__ e1w2, const float* __restrict__ e2w1,
    const float* __restrict__ e2w2, const float* __restrict__ in_w,
    const float* __restrict__ out_w, const float* __restrict__ dt_w,
    const float* __restrict__ xp_w,
    ushort_t* __restrict__ wb, float* __restrict__ dtwT,
    float* __restrict__ xpwT) {
  int i = blockIdx.x*256 + threadIdx.x;
  if (i >= PREP_TOT) return;
  if (i < CV_TOT) {
    const float* s; int off;
    if      (i < CV_O1) { s = e1w2;  off = 0; }
    else if (i < CV_O2) { s = e2w1;  off = CV_O1; }
    else if (i < CV_O3) { s = e2w2;  off = CV_O2; }
    else if (i < CV_O4) { s = in_w;  off = CV_O3; }
    else                { s = out_w; off = CV_O4; }
    wb[i] = f2bf(s[i - off]);
  } else if (i < CV_TOT + DTWT_TOT) {
    int j = i - CV_TOT;
    int layer = j / (768*24);
    int rem = j - layer*768*24;
    int d = rem / 24, r = rem - d*24;
    dtwT[layer*24*768 + r*768 + d] = dt_w[j];
  } else {
    int j = i - CV_TOT - DTWT_TOT;
    int layer = j / 49152;
    int rem = j - layer*49152;
    int r4 = rem >> 8;
    int rem2 = rem & 255;
    int e = rem2 >> 2, jj = rem2 & 3;
    xpwT[j] = (e < 56) ? xp_w[(size_t)layer*56*768 + (size_t)e*768 + r4*4 + jj] : 0.f;
  }
}

// ---------------------------------------------------------------- FPS: 4 waves/batch, packed-u64 tree argmax
__global__ __launch_bounds__(256) void fps_kernel(const float* __restrict__ xyz,
                                                  int* __restrict__ cidx) {
  const int b = blockIdx.x;
  const int tid = threadIdx.x;
  const int wave = tid >> 6, lane = tid & 63;
  __shared__ float pts[PN*3];
  __shared__ ull_t kws[2][4];
  const float* base = xyz + (size_t)b * PN * 3;
  for (int t = tid; t < PN*3; t += 256) pts[t] = base[t];
  __syncthreads();
  float px[8], py[8], pz[8], dmin[8];
  #pragma unroll
  for (int j = 0; j < 8; ++j) {
    int idx = j*256 + tid;
    px[j] = pts[idx*3+0]; py[j] = pts[idx*3+1]; pz[j] = pts[idx*3+2];
    dmin[j] = 1e10f;
  }
  int cur = 0;
  for (int g = 0; g < PG; ++g) {
    if (tid == 0) cidx[b*PG + g] = cur;
    const float cx = pts[cur*3+0], cy = pts[cur*3+1], cz = pts[cur*3+2];
    ull_t k[8];
    #pragma unroll
    for (int j = 0; j < 8; ++j) {
      float dx = __fsub_rn(px[j], cx);
      float dy = __fsub_rn(py[j], cy);
      float dz = __fsub_rn(pz[j], cz);
      float dd = __fadd_rn(__fadd_rn(__fmul_rn(dx,dx), __fmul_rn(dy,dy)), __fmul_rn(dz,dz));
      float dm = fminf(dmin[j], dd);
      dmin[j] = dm;
      k[j] = ((ull_t)__float_as_uint(dm) << 32) | (unsigned)(~(unsigned)(j*256 + tid));
    }
    ull_t a0 = umax64(k[0], k[1]), a1 = umax64(k[2], k[3]);
    ull_t a2 = umax64(k[4], k[5]), a3 = umax64(k[6], k[7]);
    ull_t K = umax64(umax64(a0, a1), umax64(a2, a3));
    #pragma unroll
    for (int off = 1; off < 64; off <<= 1)
      K = umax64(K, (ull_t)__shfl_xor((unsigned long long)K, off));
    const int par = g & 1;
    if (lane == 0) kws[par][wave] = K;
    __syncthreads();
    ull_t K0 = umax64(umax64(kws[par][0], kws[par][1]), umax64(kws[par][2], kws[par][3]));
    cur = (int)(~(unsigned)(K0 & 0xFFFFFFFFull));
  }
}

// ---------------------------------------------------------------- kNN: one wave per group, packed-u64 tree argmin
__global__ __launch_bounds__(64) void knn_kernel(const float* __restrict__ xyz,
                                                 const int* __restrict__ cidx,
                                                 float* __restrict__ nbx,
                                                 float* __restrict__ centerb) {
  const int bg = blockIdx.x;
  const int b = bg >> 7;
  const int lane = threadIdx.x;
  const float* base = xyz + (size_t)b * PN * 3;
  const int ci = cidx[bg];
  const float cx = base[ci*3+0], cy = base[ci*3+1], cz = base[ci*3+2];
  if (lane == 0) { centerb[bg*3+0]=cx; centerb[bg*3+1]=cy; centerb[bg*3+2]=cz; }
  float d2[32];
  #pragma unroll
  for (int j = 0; j < 32; ++j) {
    int idx = j*64 + lane;
    float dx = __fsub_rn(cx, base[idx*3+0]);
    float dy = __fsub_rn(cy, base[idx*3+1]);
    float dz = __fsub_rn(cz, base[idx*3+2]);
    d2[j] = __fadd_rn(__fadd_rn(__fmul_rn(dx,dx), __fmul_rn(dy,dy)), __fmul_rn(dz,dz));
  }
  for (int m = 0; m < PM; ++m) {
    ull_t t[16];
    #pragma unroll
    for (int j = 0; j < 16; ++j) {
      ull_t e0 = ((ull_t)__float_as_uint(d2[j])     << 32) | (unsigned)(j*64 + lane);
      ull_t e1 = ((ull_t)__float_as_uint(d2[j+16])  << 32) | (unsigned)((j+16)*64 + lane);
      t[j] = umin64(e0, e1);
    }
    #pragma unroll
    for (int s = 8; s >= 1; s >>= 1)
      #pragma unroll
      for (int j = 0; j < 16; ++j) if (j < s) t[j] = umin64(t[j], t[j+s]);
    ull_t K = t[0];
    #pragma unroll
    for (int off = 1; off < 64; off <<= 1)
      K = umin64(K, (ull_t)__shfl_xor((unsigned long long)K, off));
    const int k = __builtin_amdgcn_readfirstlane((int)(unsigned)(K & 0xFFFFFFFFull));
    const int jwin = k >> 6, owner = k & 63;
    #pragma unroll
    for (int j = 0; j < 32; ++j)
      if (j == jwin && lane == owner) d2[j] = 1e38f;
    if (lane == 0) {
      nbx[(bg*PM + m)*3 + 0] = base[k*3+0] - cx;
      nbx[(bg*PM + m)*3 + 1] = base[k*3+1] - cy;
      nbx[(bg*PM + m)*3 + 2] = base[k*3+2] - cz;
    }
  }
}

// ---------------------------------------------------------------- FUSED embed: stageA + stageB(MFMA) + gemmC + gemmD, all in LDS
// one block per group. concat/f3 never touch HBM.
__global__ __launch_bounds__(256) void fused_embed_kernel(
    const float* __restrict__ nbx,
    const float* __restrict__ e1w1, const float* __restrict__ e1b1,
    const float* __restrict__ bn1g, const float* __restrict__ bn1b,
    const ushort_t* __restrict__ e1w2b, const float* __restrict__ e1b2,
    const ushort_t* __restrict__ e2w1b, const float* __restrict__ e2b1,
    const float* __restrict__ bn2g, const float* __restrict__ bn2b,
    const ushort_t* __restrict__ e2w2b, const float* __restrict__ e2b2,
    float* __restrict__ tokens) {
  const int bg = blockIdx.x;
  const int tid = threadIdx.x;
  const int wid = tid >> 6, lane = tid & 63;
  const int q = lane >> 4, r16 = lane & 15;
  __shared__ float xs[PM*3];
  __shared__ __align__(16) ushort_t Af[4*2*64*8];     // 8 KB: stage-B A frags (32r x 128k)
  __shared__ __align__(16) ushort_t CAf[16*2*64*8];   // 32 KB: concat frags, then f3 frags (32r x 512k)
  __shared__ __align__(16) ushort_t Bs[32*512];       // 16 KB weight staging
  const float bns = rsqrtf(1.0f + 1e-5f);

  // ---- stage A: f1 = relu(bn(nbx @ e1w1^T + b)), written as A-fragments
  if (tid < PM*3) xs[tid] = nbx[bg*PM*3 + tid];
  __syncthreads();
  #pragma unroll
  for (int it = 0; it < 16; ++it) {
    int id = tid + it*256;
    int m = id >> 7, c = id & 127;
    float v = xs[m*3+0]*e1w1[c*3+0] + xs[m*3+1]*e1w1[c*3+1] + xs[m*3+2]*e1w1[c*3+2] + e1b1[c];
    v = fmaxf(v * (bn1g[c]*bns) + bn1b[c], 0.0f);
    int kc = c >> 5, cc = c & 31, qq = cc >> 3, j = cc & 7;
    int t = m >> 4, r = m & 15;
    Af[((kc*2 + t)*64 + qq*16 + r)*8 + j] = f2bf(v);
  }

  // ---- stage B: f2 = f1 @ e1w2^T + b2 (M=32,N=256,K=128) -> concat frags in CAf
  {
    f4 acc[2][4];
    #pragma unroll
    for (int t = 0; t < 2; ++t)
      #pragma unroll
      for (int jj = 0; jj < 4; ++jj) { f4 z = {0.f,0.f,0.f,0.f}; acc[t][jj] = z; }
    for (int kc = 0; kc < 4; ++kc) {
      #pragma unroll
      for (int u = wid; u < 16; u += 4)
        GL2L(e1w2b + (size_t)(u*16 + r16)*128 + kc*32 + q*8, Bs + u*512);
      __syncthreads();
      bf8 a0 = *(const bf8*)(Af + ((size_t)((kc*2+0)*64 + lane))*8);
      bf8 a1 = *(const bf8*)(Af + ((size_t)((kc*2+1)*64 + lane))*8);
      #pragma unroll
      for (int jj = 0; jj < 4; ++jj) {
        bf8 bv = *(const bf8*)(Bs + ((size_t)((wid*4+jj)*64 + lane))*8);
        acc[0][jj] = __builtin_amdgcn_mfma_f32_16x16x32_bf16(a0, bv, acc[0][jj], 0, 0, 0);
        acc[1][jj] = __builtin_amdgcn_mfma_f32_16x16x32_bf16(a1, bv, acc[1][jj], 0, 0, 0);
      }
      __syncthreads();
    }
    // epilogue: +bias, group max -> concat frags (cols 0..255 = fg, 256..511 = f2)
    #pragma unroll
    for (int jj = 0; jj < 4; ++jj) {
      const int n = (wid*4+jj)*16 + r16;
      const float bias = e1b2[n];
      float v0[4], v1[4];
      float cm = -1e30f;
      #pragma unroll
      for (int rr = 0; rr < 4; ++rr) {
        v0[rr] = acc[0][jj][rr] + bias;
        v1[rr] = acc[1][jj][rr] + bias;
        cm = fmaxf(cm, fmaxf(v0[rr], v1[rr]));
      }
      cm = fmaxf(cm, __shfl_xor(cm, 16));
      cm = fmaxf(cm, __shfl_xor(cm, 32));
      ushort_t mxb = f2bf(cm);
      const int c2 = 256 + n;                       // f2 col
      const int kc2 = c2 >> 5, qq2 = (c2 & 31) >> 3, j2 = c2 & 7;
      const int kc1 = n >> 5,  qq1 = (n & 31) >> 3,  j1 = n & 7;
      #pragma unroll
      for (int rr = 0; rr < 4; ++rr) {
        const int r = q*4 + rr;                     // row within tile
        CAf[((kc2*2 + 0)*64 + qq2*16 + r)*8 + j2] = f2bf(v0[rr]);
        CAf[((kc2*2 + 1)*64 + qq2*16 + r)*8 + j2] = f2bf(v1[rr]);
        CAf[((kc1*2 + 0)*64 + qq1*16 + r)*8 + j1] = mxb;
        CAf[((kc1*2 + 1)*64 + qq1*16 + r)*8 + j1] = mxb;
      }
    }
  }
  __syncthreads();

  // ---- gemmC: u = concat @ e2w1^T (M=32,N=512,K=512), bn+relu -> f3 frags in-place
  {
    f4 acc[2][8];
    #pragma unroll
    for (int t = 0; t < 2; ++t)
      #pragma unroll
      for (int jj = 0; jj < 8; ++jj) { f4 z = {0.f,0.f,0.f,0.f}; acc[t][jj] = z; }
    for (int kc = 0; kc < 16; ++kc) {
      #pragma unroll
      for (int u = wid; u < 32; u += 4)
        GL2L(e2w1b + (size_t)(u*16 + r16)*512 + kc*32 + q*8, Bs + u*512);
      __syncthreads();
      bf8 a0 = *(const bf8*)(CAf + ((size_t)((kc*2+0)*64 + lane))*8);
      bf8 a1 = *(const bf8*)(CAf + ((size_t)((kc*2+1)*64 + lane))*8);
      #pragma unroll
      for (int jj = 0; jj < 8; ++jj) {
        bf8 bv = *(const bf8*)(Bs + ((size_t)((wid*8+jj)*64 + lane))*8);
        acc[0][jj] = __builtin_amdgcn_mfma_f32_16x16x32_bf16(a0, bv, acc[0][jj], 0, 0, 0);
        acc[1][jj] = __builtin_amdgcn_mfma_f32_16x16x32_bf16(a1, bv, acc[1][jj], 0, 0, 0);
      }
      __syncthreads();
    }
    // epilogue: bn+relu, write f3 as A-fragments over CAf (dead after K-loop + barrier)
    #pragma unroll
    for (int jj = 0; jj < 8; ++jj) {
      const int n = (wid*8+jj)*16 + r16;
      const float b1 = e2b1[n], sg = bn2g[n]*bns, b2v = bn2b[n];
      const int kc = n >> 5, qq = (n & 31) >> 3, j = n & 7;
      #pragma unroll
      for (int t = 0; t < 2; ++t)
        #pragma unroll
        for (int rr = 0; rr < 4; ++rr) {
          float v = fmaxf(fmaf(acc[t][jj][rr] + b1, sg, b2v), 0.0f);
          CAf[((kc*2 + t)*64 + qq*16 + q*4 + rr)*8 + j] = f2bf(v);
        }
    }
  }
  __syncthreads();

  // ---- gemmD: f3 @ e2w2^T (M=32,N=384,K=512), +bias, group max -> token row
  {
    f4 acc[2][6];
    #pragma unroll
    for (int t = 0; t < 2; ++t)
      #pragma unroll
      for (int jj = 0; jj < 6; ++jj) { f4 z = {0.f,0.f,0.f,0.f}; acc[t][jj] = z; }
    for (int kc = 0; kc < 16; ++kc) {
      #pragma unroll
      for (int u = wid; u < 24; u += 4)
        GL2L(e2w2b + (size_t)(u*16 + r16)*512 + kc*32 + q*8, Bs + u*512);
      __syncthreads();
      bf8 a0 = *(const bf8*)(CAf + ((size_t)((kc*2+0)*64 + lane))*8);
      bf8 a1 = *(const bf8*)(CAf + ((size_t)((kc*2+1)*64 + lane))*8);
      #pragma unroll
      for (int jj = 0; jj < 6; ++jj) {
        bf8 bv = *(const bf8*)(Bs + ((size_t)((wid*6+jj)*64 + lane))*8);
        acc[0][jj] = __builtin_amdgcn_mfma_f32_16x16x32_bf16(a0, bv, acc[0][jj], 0, 0, 0);
        acc[1][jj] = __builtin_amdgcn_mfma_f32_16x16x32_bf16(a1, bv, acc[1][jj], 0, 0, 0);
      }
      __syncthreads();
    }
    #pragma unroll
    for (int jj = 0; jj < 6; ++jj) {
      const int n = (wid*6+jj)*16 + r16;
      float tm[2];
      #pragma unroll
      for (int t = 0; t < 2; ++t) {
        float v = fmaxf(fmaxf(acc[t][jj][0], acc[t][jj][1]), fmaxf(acc[t][jj][2], acc[t][jj][3]));
        v = fmaxf(v, __shfl_xor(v, 16));
        v = fmaxf(v, __shfl_xor(v, 32));
        tm[t] = v;
      }
      if (lane < 16)
        tokens[(size_t)bg*PDM + n] = fmaxf(tm[0], tm[1]) + e2b2[n];
    }
  }
}

// ---------------------------------------------------------------- bf16 MFMA GEMM, BK=64 (in-proj only)
template<int MT, int NT>
__global__ __launch_bounds__(256) void mfma_gemm(
    const ushort_t* __restrict__ A, int lda,
    const ushort_t* __restrict__ W, int ldw,
    float* __restrict__ Cf, int ldc, int K) {
  constexpr int AT = 2*MT, BT = 2*NT;
  __shared__ __align__(16) ushort_t As[2*AT*512];
  __shared__ __align__(16) ushort_t Bs[2*BT*512];
  const int tid = threadIdx.x;
  const int wid = tid >> 6, lane = tid & 63;
  const int wr = wid >> 1, wc = wid & 1;
  const int q = lane >> 4, r16 = lane & 15;
  const int m0 = blockIdx.y * (32*MT);
  const int n0 = blockIdx.x * (32*NT);
  f4 acc[MT][NT];
  #pragma unroll
  for (int i = 0; i < MT; ++i)
    #pragma unroll
    for (int j = 0; j < NT; ++j) { f4 z = {0.f,0.f,0.f,0.f}; acc[i][j] = z; }

  for (int k0 = 0; k0 < K; k0 += 64) {
    #pragma unroll
    for (int c = 0; c < 2; ++c) {
      const int kk = k0 + c*32 + q*8;
      #pragma unroll
      for (int t = wid; t < AT; t += 4)
        GL2L(A + (size_t)(m0 + t*16 + r16)*lda + kk, As + (c*AT + t)*512);
      #pragma unroll
      for (int t = wid; t < BT; t += 4)
        GL2L(W + (size_t)(n0 + t*16 + r16)*ldw + kk, Bs + (c*BT + t)*512);
    }
    __syncthreads();
    #pragma unroll
    for (int c = 0; c < 2; ++c) {
      bf8 af[MT], bfr[NT];
      #pragma unroll
      for (int i = 0; i < MT; ++i)
        af[i] = *(const bf8*)(As + ((size_t)(c*AT + wr*MT+i)*64 + lane)*8);
      #pragma unroll
      for (int j = 0; j < NT; ++j)
        bfr[j] = *(const bf8*)(Bs + ((size_t)(c*BT + wc*NT+j)*64 + lane)*8);
      #pragma unroll
      for (int i = 0; i < MT; ++i)
        #pragma unroll
        for (int j = 0; j < NT; ++j)
          acc[i][j] = __builtin_amdgcn_mfma_f32_16x16x32_bf16(af[i], bfr[j], acc[i][j], 0, 0, 0);
    }
    __syncthreads();
  }
  #pragma unroll
  for (int i = 0; i < MT; ++i) {
    const int row = m0 + (wr*MT+i)*16 + q*4;
    #pragma unroll
    for (int j = 0; j < NT; ++j) {
      const int col = n0 + (wc*NT+j)*16 + r16;
      #pragma unroll
      for (int r = 0; r < 4; ++r)
        Cf[(size_t)(row+r)*ldc + col] = acc[i][j][r];
    }
  }
}

// ---------------------------------------------------------------- out-proj + residual + LN fused
__global__ __launch_bounds__(256) void outproj_ln_kernel(
    const ushort_t* __restrict__ A,
    const ushort_t* __restrict__ W,
    float* __restrict__ resid,
    const float* __restrict__ w, const float* __restrict__ bb,
    ushort_t* __restrict__ xo, float* __restrict__ fout, int last) {
  constexpr int BT = 24;
  __shared__ __align__(16) ushort_t As[2*2*512];
  __shared__ __align__(16) ushort_t Bs[2*BT*512];
  __shared__ float rsum[32][2];
  __shared__ float rsq[32][2];
  const int tid = threadIdx.x;
  const int wid = tid >> 6, lane = tid & 63;
  const int wr = wid >> 1, wc = wid & 1;
  const int q = lane >> 4, r16 = lane & 15;
  const int m0 = blockIdx.x * 32;
  f4 acc[12];
  #pragma unroll
  for (int j = 0; j < 12; ++j) { f4 z = {0.f,0.f,0.f,0.f}; acc[j] = z; }

  for (int k0 = 0; k0 < 768; k0 += 64) {
    #pragma unroll
    for (int c = 0; c < 2; ++c) {
      const int kk = k0 + c*32 + q*8;
      if (wid < 2)
        GL2L(A + (size_t)(m0 + wid*16 + r16)*768 + kk, As + (c*2 + wid)*512);
      #pragma unroll
      for (int t = wid; t < BT; t += 4)
        GL2L(W + (size_t)(t*16 + r16)*768 + kk, Bs + (c*BT + t)*512);
    }
    __syncthreads();
    #pragma unroll
    for (int c = 0; c < 2; ++c) {
      bf8 af = *(const bf8*)(As + ((size_t)(c*2 + wr)*64 + lane)*8);
      #pragma unroll
      for (int j = 0; j < 12; ++j) {
        bf8 bv = *(const bf8*)(Bs + ((size_t)(c*BT + wc*12 + j)*64 + lane)*8);
        acc[j] = __builtin_amdgcn_mfma_f32_16x16x32_bf16(af, bv, acc[j], 0, 0, 0);
      }
    }
    __syncthreads();
  }

  const int rl = wr*16 + q*4;
  #pragma unroll
  for (int r = 0; r < 4; ++r) {
    const size_t grow = (size_t)(m0 + rl + r)*384;
    #pragma unroll
    for (int j = 0; j < 12; ++j) {
      const int col = wc*192 + j*16 + r16;
      float t = acc[j][r] + resid[grow + col];
      acc[j][r] = t;
      resid[grow + col] = t;
    }
  }
  float ps[4];
  #pragma unroll
  for (int r = 0; r < 4; ++r) {
    float a = 0.f;
    #pragma unroll
    for (int j = 0; j < 12; ++j) a += acc[j][r];
    #pragma unroll
    for (int off = 1; off < 16; off <<= 1) a += __shfl_xor(a, off);
    ps[r] = a;
  }
  if (r16 == 0) {
    #pragma unroll
    for (int r = 0; r < 4; ++r) rsum[rl + r][wc] = ps[r];
  }
  __syncthreads();
  float mu[4];
  #pragma unroll
  for (int r = 0; r < 4; ++r) mu[r] = (rsum[rl+r][0] + rsum[rl+r][1]) * (1.0f/384.0f);
  #pragma unroll
  for (int r = 0; r < 4; ++r) {
    float a = 0.f;
    #pragma unroll
    for (int j = 0; j < 12; ++j) { float d = acc[j][r] - mu[r]; a += d*d; }
    #pragma unroll
    for (int off = 1; off < 16; off <<= 1) a += __shfl_xor(a, off);
    ps[r] = a;
  }
  if (r16 == 0) {
    #pragma unroll
    for (int r = 0; r < 4; ++r) rsq[rl + r][wc] = ps[r];
  }
  __syncthreads();
  #pragma unroll
  for (int r = 0; r < 4; ++r) {
    const float rs = rsqrtf((rsq[rl+r][0] + rsq[rl+r][1]) * (1.0f/384.0f) + 1e-5f);
    const size_t grow = (size_t)(m0 + rl + r)*384;
    #pragma unroll
    for (int j = 0; j < 12; ++j) {
      const int col = wc*192 + j*16 + r16;
      float o = (acc[j][r] - mu[r]) * rs * w[col] + bb[col];
      if (last) fout[grow + col] = o;
      else      xo[grow + col] = f2bf(o);
    }
  }
}

// ---------------------------------------------------------------- prenorm0: pos-MLP + resid init + LN -> bf16
__global__ __launch_bounds__(128) void prenorm0_kernel(
    const float* __restrict__ h, const float* __restrict__ centerb,
    const float* __restrict__ pw1, const float* __restrict__ pb1,
    const float* __restrict__ pw2, const float* __restrict__ pb2,
    float* __restrict__ res,
    const float* __restrict__ w, const float* __restrict__ bb,
    ushort_t* __restrict__ xo) {
  const int row = blockIdx.x;
  const int tid = threadIdx.x;
  __shared__ float t1[128];
  __shared__ float s1[2], s2[2];
  const float cx = centerb[row*3+0], cy = centerb[row*3+1], cz = centerb[row*3+2];
  {
    const int c = tid;
    float v = cx*pw1[c*3+0] + cy*pw1[c*3+1] + cz*pw1[c*3+2] + pb1[c];
    float u = 0.7978845608028654f * (v + 0.044715f*v*v*v);
    t1[c] = 0.5f*v*(1.0f + tanhf(u));
  }
  __syncthreads();
  float v[3];
  #pragma unroll
  for (int i = 0; i < 3; ++i) {
    int j = tid + i*128;
    float acc = pb2[j];
    const float4* wp = (const float4*)(pw2 + (size_t)j*128);
    const float4* a = (const float4*)t1;
    for (int k4 = 0; k4 < 32; ++k4) {
      float4 wv = wp[k4], av = a[k4];
      acc = fmaf(av.x, wv.x, fmaf(av.y, wv.y, fmaf(av.z, wv.z, fmaf(av.w, wv.w, acc))));
    }
    float r = h[(size_t)row*PDM + j] + acc;
    res[(size_t)row*PDM + j] = r;
    v[i] = r;
  }
  float ss = v[0] + v[1] + v[2];
  #pragma unroll
  for (int off = 1; off < 64; off <<= 1) ss += __shfl_xor(ss, off);
  if ((tid & 63) == 0) s1[tid>>6] = ss;
  __syncthreads();
  const float mu = (s1[0] + s1[1]) * (1.0f/384.0f);
  float qq = 0.f;
  #pragma unroll
  for (int i = 0; i < 3; ++i) { float d = v[i] - mu; qq += d*d; }
  #pragma unroll
  for (int off = 1; off < 64; off <<= 1) qq += __shfl_xor(qq, off);
  if ((tid & 63) == 0) s2[tid>>6] = qq;
  __syncthreads();
  const float rs = rsqrtf((s2[0] + s2[1]) * (1.0f/384.0f) + 1e-5f);
  #pragma unroll
  for (int i = 0; i < 3; ++i) {
    int j = tid + i*128;
    xo[(size_t)row*PDM + j] = f2bf((v[i] - mu) * rs * w[j] + bb[j]);
  }
}

// ---------------------------------------------------------------- fused conv+silu + xp (coalesced) + dt
__global__ __launch_bounds__(256) void cxd_kernel(
    const float* __restrict__ xz,
    const float* __restrict__ cw, const float* __restrict__ cb,
    const float* __restrict__ xpwT,
    const float* __restrict__ dtwT, const float* __restrict__ dtbias,
    float* __restrict__ xin, float* __restrict__ dbl, float* __restrict__ dtg) {
  const int row = blockIdx.x;
  const int tid = threadIdx.x;
  const int wid = tid >> 6, lane = tid & 63;
  const int l = row & 127;
  const int bb = row - l;
  __shared__ float xin_s[PDI];
  __shared__ float part[4][64];
  __shared__ float dbl_s[64];
  #pragma unroll
  for (int i = 0; i < 3; ++i) {
    const int d = tid + i*256;
    float acc = cb[d];
    #pragma unroll
    for (int k = 0; k < 4; ++k) {
      int ll = l + k - 3;
      if (ll >= 0) acc = fmaf(xz[(size_t)(bb+ll)*1536 + d], cw[d*4+k], acc);
    }
    float s = 1.0f / (1.0f + __expf(-acc));
    float v = acc * s;
    xin_s[d] = v;
    xin[(size_t)row*PDI + d] = v;
  }
  __syncthreads();
  {
    const float4* wp = (const float4*)xpwT;
    float a = 0.f;
    const int base_r4 = wid*48;
    for (int t = 0; t < 48; ++t) {
      const int r4 = base_r4 + t;
      float4 w4 = wp[r4*64 + lane];
      float4 x4 = *(const float4*)&xin_s[r4*4];
      a = fmaf(x4.x, w4.x, fmaf(x4.y, w4.y, fmaf(x4.z, w4.z, fmaf(x4.w, w4.w, a))));
    }
    part[wid][lane] = a;
  }
  __syncthreads();
  if (tid < 64) {
    float v = part[0][tid] + part[1][tid] + part[2][tid] + part[3][tid];
    dbl_s[tid] = v;
    if (tid < 56) dbl[(size_t)row*56 + tid] = v;
  }
  __syncthreads();
  #pragma unroll
  for (int i = 0; i < 3; ++i) {
    const int d = tid + i*256;
    float acc = dtbias[d];
    #pragma unroll
    for (int r = 0; r < 24; ++r) acc = fmaf(dbl_s[r], dtwT[r*768 + d], acc);
    dtg[(size_t)row*PDI + d] = log1pf(expf(-fabsf(acc))) + fmaxf(acc, 0.0f);
  }
}

// ---------------------------------------------------------------- selective scan + gate -> bf16 (prefetched)
__global__ __launch_bounds__(256) void scan_kernel(const float* __restrict__ dt,
                                                   const float* __restrict__ xin,
                                                   const float* __restrict__ dbl,
                                                   const float* __restrict__ alog,
                                                   const float* __restrict__ dp,
                                                   const float* __restrict__ xz,
                                                   ushort_t* __restrict__ yb) {
  const int s = threadIdx.x & 15;
  const int dl = threadIdx.x >> 4;
  const int d = blockIdx.x*16 + dl;
  const int b = blockIdx.y;
  const float A = -expf(alog[d*16 + s]);
  const float Dv = dp[d];
  float h = 0.f;
  int ro = b*128;
  float dtv = dt[(size_t)ro*PDI + d];
  float xv  = xin[(size_t)ro*PDI + d];
  float Bv  = dbl[(size_t)ro*56 + 24 + s];
  float Cv  = dbl[(size_t)ro*56 + 40 + s];
  float zv  = xz[(size_t)ro*1536 + 768 + d];
  for (int l = 0; l < 128; ++l) {
    float ndt = 0.f, nxv = 0.f, nBv = 0.f, nCv = 0.f, nz = 0.f;
    const int r2 = ro + 1;
    if (l < 127) {
      ndt = dt[(size_t)r2*PDI + d];
      nxv = xin[(size_t)r2*PDI + d];
      nBv = dbl[(size_t)r2*56 + 24 + s];
      nCv = dbl[(size_t)r2*56 + 40 + s];
      nz  = xz[(size_t)r2*1536 + 768 + d];
    }
    float dA = __expf(dtv * A);
    h = fmaf(dA, h, dtv * xv * Bv);
    float p = h * Cv;
    p += __shfl_xor(p, 1);
    p += __shfl_xor(p, 2);
    p += __shfl_xor(p, 4);
    p += __shfl_xor(p, 8);
    if (s == 0) {
      float sg = 1.0f / (1.0f + __expf(-zv));
      yb[(size_t)ro*PDI + d] = f2bf(fmaf(Dv, xv, p) * zv * sg);
    }
    dtv = ndt; xv = nxv; Bv = nBv; Cv = nCv; zv = nz;
    ro = r2;
  }
}

// ---------------------------------------------------------------- host
extern "C" void kernel_launch(void* const* d_in, const int* in_sizes, int n_in,
                              void* d_out, int out_size, void* d_ws, size_t ws_size,
                              hipStream_t stream) {
  const float* xyz    = (const float*)d_in[0];
  const float* e1w1   = (const float*)d_in[1];
  const float* e1b1   = (const float*)d_in[2];
  const float* bn1g   = (const float*)d_in[3];
  const float* bn1b   = (const float*)d_in[4];
  const float* e1w2   = (const float*)d_in[5];
  const float* e1b2   = (const float*)d_in[6];
  const float* e2w1   = (const float*)d_in[7];
  const float* e2b1   = (const float*)d_in[8];
  const float* bn2g   = (const float*)d_in[9];
  const float* bn2b   = (const float*)d_in[10];
  const float* e2w2   = (const float*)d_in[11];
  const float* e2b2   = (const float*)d_in[12];
  const float* pw1    = (const float*)d_in[13];
  const float* pb1    = (const float*)d_in[14];
  const float* pw2    = (const float*)d_in[15];
  const float* pb2    = (const float*)d_in[16];
  const float* in_w   = (const float*)d_in[17];
  const float* conv_w = (const float*)d_in[18];
  const float* conv_b = (const float*)d_in[19];
  const float* xp_w   = (const float*)d_in[20];
  const float* dt_w   = (const float*)d_in[21];
  const float* dt_b   = (const float*)d_in[22];
  const float* A_log  = (const float*)d_in[23];
  const float* Dp     = (const float*)d_in[24];
  const float* out_w  = (const float*)d_in[25];
  const float* lnw    = (const float*)d_in[26];
  const float* lnb    = (const float*)d_in[27];
  const float* fnw    = (const float*)d_in[28];
  const float* fnb    = (const float*)d_in[29];

  char* ws = (char*)d_ws;
  size_t off = 0;
  auto alloc = [&](size_t bytes) { void* p = ws + off; off += (bytes + 255) & ~(size_t)255; return p; };
  int*      cidx    = (int*)     alloc(PB*PG*4);
  float*    centerb = (float*)   alloc(ROWS*3*4);
  float*    nbx     = (float*)   alloc(ROWS*PM*3*4);
  float*    hbuf    = (float*)   alloc((size_t)ROWS*PDM*4);
  float*    resid   = (float*)   alloc((size_t)ROWS*PDM*4);
  ushort_t* xlnb    = (ushort_t*)alloc((size_t)ROWS*PDM*2);
  float*    xz      = (float*)   alloc((size_t)ROWS*1536*4);
  float*    xin     = (float*)   alloc((size_t)ROWS*PDI*4);
  float*    dbl     = (float*)   alloc((size_t)ROWS*56*4);
  float*    dtg     = (float*)   alloc((size_t)ROWS*PDI*4);
  ushort_t* ybufb   = (ushort_t*)alloc((size_t)ROWS*PDI*2);
  ushort_t* wb      = (ushort_t*)alloc((size_t)CV_TOT*2);
  float*    dtwT    = (float*)   alloc((size_t)DTWT_TOT*4);
  float*    xpwT    = (float*)   alloc((size_t)XPWT_TOT*4);

  ushort_t* e1w2b  = wb;
  ushort_t* e2w1b  = wb + CV_O1;
  ushort_t* e2w2b  = wb + CV_O2;
  ushort_t* in_wb  = wb + CV_O3;
  ushort_t* out_wb = wb + CV_O4;

  prep_kernel<<<(PREP_TOT+255)/256, 256, 0, stream>>>(
      e1w2, e2w1, e2w2, in_w, out_w, dt_w, xp_w, wb, dtwT, xpwT);

  fps_kernel<<<PB, 256, 0, stream>>>(xyz, cidx);
  knn_kernel<<<ROWS, 64, 0, stream>>>(xyz, cidx, nbx, centerb);
  fused_embed_kernel<<<ROWS, 256, 0, stream>>>(
      nbx, e1w1, e1b1, bn1g, bn1b, e1w2b, e1b2,
      e2w1b, e2b1, bn2g, bn2b, e2w2b, e2b2, hbuf);

  prenorm0_kernel<<<ROWS, 128, 0, stream>>>(hbuf, centerb, pw1, pb1, pw2, pb2,
                                            resid, lnw, lnb, xlnb);

  for (int i = 0; i < 12; ++i) {
    mfma_gemm<4,4><<<dim3(12, 16), 256, 0, stream>>>(
        xlnb, PDM, in_wb + (size_t)i*1536*384, PDM, xz, 1536, PDM);
    cxd_kernel<<<ROWS, 256, 0, stream>>>(
        xz, conv_w + (size_t)i*768*4, conv_b + (size_t)i*768,
        xpwT + (size_t)i*49152, dtwT + (size_t)i*24*768, dt_b + (size_t)i*768,
        xin, dbl, dtg);
    scan_kernel<<<dim3(48, PB), 256, 0, stream>>>(
        dtg, xin, dbl, A_log + (size_t)i*768*16, Dp + (size_t)i*768, xz, ybufb);
    const int last = (i == 11);
    outproj_ln_kernel<<<64, 256, 0, stream>>>(
        ybufb, out_wb + (size_t)i*384*768, resid,
        last ? fnw : (lnw + (i+1)*384), last ? fnb : (lnb + (i+1)*384),
        xlnb, (float*)d_out, last);
  }
}

// Round 7
// 1840.795 us; speedup vs baseline: 1.1766x; 1.1766x over previous
//
#include <hip/hip_runtime.h>
#include <hip/hip_bf16.h>
#include <math.h>

#define PN   2048
#define PB   16
#define PG   128
#define PM   32
#define PDM  384
#define PDI  768
#define ROWS 2048   // B*G == B*L

typedef unsigned short ushort_t;
typedef unsigned long long ull_t;
typedef __attribute__((ext_vector_type(8))) short bf8;
typedef __attribute__((ext_vector_type(4))) float f4;

__device__ __forceinline__ ushort_t f2bf(float x) {
  unsigned int u = __float_as_uint(x);
  unsigned int r = (u + 0x7FFFu + ((u >> 16) & 1u)) >> 16;
  return (ushort_t)r;
}
__device__ __forceinline__ ull_t umax64(ull_t a, ull_t b) { return a > b ? a : b; }
__device__ __forceinline__ ull_t umin64(ull_t a, ull_t b) { return a < b ? a : b; }

#define GL2L(gp, lp) __builtin_amdgcn_global_load_lds((const __attribute__((address_space(1))) void*)(gp), (__attribute__((address_space(3))) void*)(lp), 16, 0, 0)

// ---------------------------------------------------------------- prep
#define CV_O1 32768
#define CV_O2 294912
#define CV_O3 491520
#define CV_O4 7569408
#define CV_TOT 11108352
#define DTWT_TOT (12*768*24)
#define XPWT_TOT (12*192*64*4)
#define PREP_TOT (CV_TOT + DTWT_TOT + XPWT_TOT)
__global__ __launch_bounds__(256) void prep_kernel(
    const float* __restrict__ e1w2, const float* __restrict__ e2w1,
    const float* __restrict__ e2w2, const float* __restrict__ in_w,
    const float* __restrict__ out_w, const float* __restrict__ dt_w,
    const float* __restrict__ xp_w,
    ushort_t* __restrict__ wb, float* __restrict__ dtwT,
    float* __restrict__ xpwT) {
  int i = blockIdx.x*256 + threadIdx.x;
  if (i >= PREP_TOT) return;
  if (i < CV_TOT) {
    const float* s; int off;
    if      (i < CV_O1) { s = e1w2;  off = 0; }
    else if (i < CV_O2) { s = e2w1;  off = CV_O1; }
    else if (i < CV_O3) { s = e2w2;  off = CV_O2; }
    else if (i < CV_O4) { s = in_w;  off = CV_O3; }
    else                { s = out_w; off = CV_O4; }
    wb[i] = f2bf(s[i - off]);
  } else if (i < CV_TOT + DTWT_TOT) {
    int j = i - CV_TOT;
    int layer = j / (768*24);
    int rem = j - layer*768*24;
    int d = rem / 24, r = rem - d*24;
    dtwT[layer*24*768 + r*768 + d] = dt_w[j];
  } else {
    int j = i - CV_TOT - DTWT_TOT;
    int layer = j / 49152;
    int rem = j - layer*49152;
    int r4 = rem >> 8;
    int rem2 = rem & 255;
    int e = rem2 >> 2, jj = rem2 & 3;
    xpwT[j] = (e < 56) ? xp_w[(size_t)layer*56*768 + (size_t)e*768 + r4*4 + jj] : 0.f;
  }
}

// ---------------------------------------------------------------- FPS: 4 waves/batch, packed-u64 tree argmax
__global__ __launch_bounds__(256) void fps_kernel(const float* __restrict__ xyz,
                                                  int* __restrict__ cidx) {
  const int b = blockIdx.x;
  const int tid = threadIdx.x;
  const int wave = tid >> 6, lane = tid & 63;
  __shared__ float pts[PN*3];
  __shared__ ull_t kws[2][4];
  const float* base = xyz + (size_t)b * PN * 3;
  for (int t = tid; t < PN*3; t += 256) pts[t] = base[t];
  __syncthreads();
  float px[8], py[8], pz[8], dmin[8];
  #pragma unroll
  for (int j = 0; j < 8; ++j) {
    int idx = j*256 + tid;
    px[j] = pts[idx*3+0]; py[j] = pts[idx*3+1]; pz[j] = pts[idx*3+2];
    dmin[j] = 1e10f;
  }
  int cur = 0;
  for (int g = 0; g < PG; ++g) {
    if (tid == 0) cidx[b*PG + g] = cur;
    const float cx = pts[cur*3+0], cy = pts[cur*3+1], cz = pts[cur*3+2];
    ull_t k[8];
    #pragma unroll
    for (int j = 0; j < 8; ++j) {
      float dx = __fsub_rn(px[j], cx);
      float dy = __fsub_rn(py[j], cy);
      float dz = __fsub_rn(pz[j], cz);
      float dd = __fadd_rn(__fadd_rn(__fmul_rn(dx,dx), __fmul_rn(dy,dy)), __fmul_rn(dz,dz));
      float dm = fminf(dmin[j], dd);
      dmin[j] = dm;
      k[j] = ((ull_t)__float_as_uint(dm) << 32) | (unsigned)(~(unsigned)(j*256 + tid));
    }
    ull_t a0 = umax64(k[0], k[1]), a1 = umax64(k[2], k[3]);
    ull_t a2 = umax64(k[4], k[5]), a3 = umax64(k[6], k[7]);
    ull_t K = umax64(umax64(a0, a1), umax64(a2, a3));
    #pragma unroll
    for (int off = 1; off < 64; off <<= 1)
      K = umax64(K, (ull_t)__shfl_xor((unsigned long long)K, off));
    const int par = g & 1;
    if (lane == 0) kws[par][wave] = K;
    __syncthreads();
    ull_t K0 = umax64(umax64(kws[par][0], kws[par][1]), umax64(kws[par][2], kws[par][3]));
    cur = (int)(~(unsigned)(K0 & 0xFFFFFFFFull));
  }
}

// ---------------------------------------------------------------- kNN: one wave per group, packed-u64 tree argmin
__global__ __launch_bounds__(64) void knn_kernel(const float* __restrict__ xyz,
                                                 const int* __restrict__ cidx,
                                                 float* __restrict__ nbx,
                                                 float* __restrict__ centerb) {
  const int bg = blockIdx.x;
  const int b = bg >> 7;
  const int lane = threadIdx.x;
  const float* base = xyz + (size_t)b * PN * 3;
  const int ci = cidx[bg];
  const float cx = base[ci*3+0], cy = base[ci*3+1], cz = base[ci*3+2];
  if (lane == 0) { centerb[bg*3+0]=cx; centerb[bg*3+1]=cy; centerb[bg*3+2]=cz; }
  float d2[32];
  #pragma unroll
  for (int j = 0; j < 32; ++j) {
    int idx = j*64 + lane;
    float dx = __fsub_rn(cx, base[idx*3+0]);
    float dy = __fsub_rn(cy, base[idx*3+1]);
    float dz = __fsub_rn(cz, base[idx*3+2]);
    d2[j] = __fadd_rn(__fadd_rn(__fmul_rn(dx,dx), __fmul_rn(dy,dy)), __fmul_rn(dz,dz));
  }
  for (int m = 0; m < PM; ++m) {
    ull_t t[16];
    #pragma unroll
    for (int j = 0; j < 16; ++j) {
      ull_t e0 = ((ull_t)__float_as_uint(d2[j])     << 32) | (unsigned)(j*64 + lane);
      ull_t e1 = ((ull_t)__float_as_uint(d2[j+16])  << 32) | (unsigned)((j+16)*64 + lane);
      t[j] = umin64(e0, e1);
    }
    #pragma unroll
    for (int s = 8; s >= 1; s >>= 1)
      #pragma unroll
      for (int j = 0; j < 16; ++j) if (j < s) t[j] = umin64(t[j], t[j+s]);
    ull_t K = t[0];
    #pragma unroll
    for (int off = 1; off < 64; off <<= 1)
      K = umin64(K, (ull_t)__shfl_xor((unsigned long long)K, off));
    const int k = __builtin_amdgcn_readfirstlane((int)(unsigned)(K & 0xFFFFFFFFull));
    const int jwin = k >> 6, owner = k & 63;
    #pragma unroll
    for (int j = 0; j < 32; ++j)
      if (j == jwin && lane == owner) d2[j] = 1e38f;
    if (lane == 0) {
      nbx[(bg*PM + m)*3 + 0] = base[k*3+0] - cx;
      nbx[(bg*PM + m)*3 + 1] = base[k*3+1] - cy;
      nbx[(bg*PM + m)*3 + 2] = base[k*3+2] - cz;
    }
  }
}

// ---------------------------------------------------------------- embed stage A+B -> f2 (bf16 rows) + fg (group max)
__global__ __launch_bounds__(256) void embed1_kernel(
    const float* __restrict__ nbx,
    const float* __restrict__ e1w1, const float* __restrict__ e1b1,
    const float* __restrict__ bn1g, const float* __restrict__ bn1b,
    const ushort_t* __restrict__ e1w2b, const float* __restrict__ e1b2,
    ushort_t* __restrict__ f2b, ushort_t* __restrict__ fgb) {
  const int bg = blockIdx.x;
  const int tid = threadIdx.x;
  const int wid = tid >> 6, lane = tid & 63;
  const int q = lane >> 4, r16 = lane & 15;
  __shared__ float xs[PM*3];
  __shared__ __align__(16) ushort_t Af[4*2*64*8];
  __shared__ __align__(16) ushort_t Bs[16*64*8];
  if (tid < PM*3) xs[tid] = nbx[bg*PM*3 + tid];
  __syncthreads();
  const float bns = rsqrtf(1.0f + 1e-5f);
  #pragma unroll
  for (int it = 0; it < 16; ++it) {
    int id = tid + it*256;
    int m = id >> 7, c = id & 127;
    float v = xs[m*3+0]*e1w1[c*3+0] + xs[m*3+1]*e1w1[c*3+1] + xs[m*3+2]*e1w1[c*3+2] + e1b1[c];
    v = fmaxf(v * (bn1g[c]*bns) + bn1b[c], 0.0f);
    int kc = c >> 5, cc = c & 31, qq = cc >> 3, j = cc & 7;
    int t = m >> 4, r = m & 15;
    Af[((kc*2 + t)*64 + qq*16 + r)*8 + j] = f2bf(v);
  }
  f4 acc[2][4];
  #pragma unroll
  for (int t = 0; t < 2; ++t)
    #pragma unroll
    for (int jj = 0; jj < 4; ++jj) { f4 z = {0.f,0.f,0.f,0.f}; acc[t][jj] = z; }
  for (int kc = 0; kc < 4; ++kc) {
    #pragma unroll
    for (int u = wid; u < 16; u += 4)
      GL2L(e1w2b + (size_t)(u*16 + r16)*128 + kc*32 + q*8, Bs + u*512);
    __syncthreads();
    bf8 a0 = *(const bf8*)(Af + ((size_t)((kc*2+0)*64 + lane))*8);
    bf8 a1 = *(const bf8*)(Af + ((size_t)((kc*2+1)*64 + lane))*8);
    #pragma unroll
    for (int jj = 0; jj < 4; ++jj) {
      bf8 bv = *(const bf8*)(Bs + ((size_t)((wid*4+jj)*64 + lane))*8);
      acc[0][jj] = __builtin_amdgcn_mfma_f32_16x16x32_bf16(a0, bv, acc[0][jj], 0, 0, 0);
      acc[1][jj] = __builtin_amdgcn_mfma_f32_16x16x32_bf16(a1, bv, acc[1][jj], 0, 0, 0);
    }
    __syncthreads();
  }
  #pragma unroll
  for (int jj = 0; jj < 4; ++jj) {
    const int n = (wid*4+jj)*16 + r16;
    const float bias = e1b2[n];
    float v0[4], v1[4];
    float cm = -1e30f;
    #pragma unroll
    for (int rr = 0; rr < 4; ++rr) {
      v0[rr] = acc[0][jj][rr] + bias;
      v1[rr] = acc[1][jj][rr] + bias;
      cm = fmaxf(cm, fmaxf(v0[rr], v1[rr]));
    }
    cm = fmaxf(cm, __shfl_xor(cm, 16));
    cm = fmaxf(cm, __shfl_xor(cm, 32));
    #pragma unroll
    for (int rr = 0; rr < 4; ++rr) {
      f2b[((size_t)bg*32 + q*4 + rr)*256 + n]      = f2bf(v0[rr]);
      f2b[((size_t)bg*32 + 16 + q*4 + rr)*256 + n] = f2bf(v1[rr]);
    }
    if (lane < 16) fgb[(size_t)bg*256 + n] = f2bf(cm);
  }
}

// ---------------------------------------------------------------- bf16 MFMA GEMM, BK=64
// EPI 0: fp32 store. EPI 1: relu(bn(acc + p3[group] + p0)) -> bf16 (gemmC').
// EPI 2: group(32-row) max + p0 -> fp32 tokens (MT=4).
template<int MT, int NT, int EPI>
__global__ __launch_bounds__(256) void mfma_gemm(
    const ushort_t* __restrict__ A, int lda,
    const ushort_t* __restrict__ W, int ldw,
    float* __restrict__ Cf, ushort_t* __restrict__ Cb, int ldc, int K,
    const float* __restrict__ p0, const float* __restrict__ p1,
    const float* __restrict__ p2, const float* __restrict__ p3) {
  static_assert(EPI != 2 || MT == 4, "groupmax needs MT=4");
  constexpr int AT = 2*MT, BT = 2*NT;
  __shared__ __align__(16) ushort_t As[2*AT*512];
  __shared__ __align__(16) ushort_t Bs[2*BT*512];
  const int tid = threadIdx.x;
  const int wid = tid >> 6, lane = tid & 63;
  const int wr = wid >> 1, wc = wid & 1;
  const int q = lane >> 4, r16 = lane & 15;
  const int m0 = blockIdx.y * (32*MT);
  const int n0 = blockIdx.x * (32*NT);
  f4 acc[MT][NT];
  #pragma unroll
  for (int i = 0; i < MT; ++i)
    #pragma unroll
    for (int j = 0; j < NT; ++j) { f4 z = {0.f,0.f,0.f,0.f}; acc[i][j] = z; }

  for (int k0 = 0; k0 < K; k0 += 64) {
    #pragma unroll
    for (int c = 0; c < 2; ++c) {
      const int kk = k0 + c*32 + q*8;
      #pragma unroll
      for (int t = wid; t < AT; t += 4)
        GL2L(A + (size_t)(m0 + t*16 + r16)*lda + kk, As + (c*AT + t)*512);
      #pragma unroll
      for (int t = wid; t < BT; t += 4)
        GL2L(W + (size_t)(n0 + t*16 + r16)*ldw + kk, Bs + (c*BT + t)*512);
    }
    __syncthreads();
    #pragma unroll
    for (int c = 0; c < 2; ++c) {
      bf8 af[MT], bfr[NT];
      #pragma unroll
      for (int i = 0; i < MT; ++i)
        af[i] = *(const bf8*)(As + ((size_t)(c*AT + wr*MT+i)*64 + lane)*8);
      #pragma unroll
      for (int j = 0; j < NT; ++j)
        bfr[j] = *(const bf8*)(Bs + ((size_t)(c*BT + wc*NT+j)*64 + lane)*8);
      #pragma unroll
      for (int i = 0; i < MT; ++i)
        #pragma unroll
        for (int j = 0; j < NT; ++j)
          acc[i][j] = __builtin_amdgcn_mfma_f32_16x16x32_bf16(af[i], bfr[j], acc[i][j], 0, 0, 0);
    }
    __syncthreads();
  }

  if constexpr (EPI == 0) {
    #pragma unroll
    for (int i = 0; i < MT; ++i) {
      const int row = m0 + (wr*MT+i)*16 + q*4;
      #pragma unroll
      for (int j = 0; j < NT; ++j) {
        const int col = n0 + (wc*NT+j)*16 + r16;
        #pragma unroll
        for (int r = 0; r < 4; ++r)
          Cf[(size_t)(row+r)*ldc + col] = acc[i][j][r];
      }
    }
  } else if constexpr (EPI == 1) {
    const float bns = rsqrtf(1.0f + 1e-5f);
    #pragma unroll
    for (int j = 0; j < NT; ++j) {
      const int col = n0 + (wc*NT+j)*16 + r16;
      const float b1 = p0[col], sg = p1[col]*bns, b2 = p2[col];
      #pragma unroll
      for (int i = 0; i < MT; ++i) {
        const int row = m0 + (wr*MT+i)*16 + q*4;
        #pragma unroll
        for (int r = 0; r < 4; ++r) {
          const int grp = (row + r) >> 5;
          float v = fmaxf(fmaf(acc[i][j][r] + b1 + p3[(size_t)grp*512 + col], sg, b2), 0.0f);
          Cb[(size_t)(row+r)*ldc + col] = f2bf(v);
        }
      }
    }
  } else {
    #pragma unroll
    for (int j = 0; j < NT; ++j) {
      const int col = n0 + (wc*NT+j)*16 + r16;
      float tm[4];
      #pragma unroll
      for (int i = 0; i < 4; ++i) {
        float t = fmaxf(fmaxf(acc[i][j][0], acc[i][j][1]), fmaxf(acc[i][j][2], acc[i][j][3]));
        t = fmaxf(t, __shfl_xor(t, 16));
        t = fmaxf(t, __shfl_xor(t, 32));
        tm[i] = t;
      }
      const float bias = p0[col];
      if (lane < 16) {
        const int g0 = (m0 >> 5) + wr*2;
        Cf[(size_t)g0*ldc + col]     = fmaxf(tm[0], tm[1]) + bias;
        Cf[(size_t)(g0+1)*ldc + col] = fmaxf(tm[2], tm[3]) + bias;
      }
    }
  }
}

// ---------------------------------------------------------------- prenorm0: pos-MLP + resid init + LN -> bf16
__global__ __launch_bounds__(128) void prenorm0_kernel(
    const float* __restrict__ h, const float* __restrict__ centerb,
    const float* __restrict__ pw1, const float* __restrict__ pb1,
    const float* __restrict__ pw2, const float* __restrict__ pb2,
    float* __restrict__ res,
    const float* __restrict__ w, const float* __restrict__ bb,
    ushort_t* __restrict__ xo) {
  const int row = blockIdx.x;
  const int tid = threadIdx.x;
  __shared__ float t1[128];
  __shared__ float s1[2], s2[2];
  const float cx = centerb[row*3+0], cy = centerb[row*3+1], cz = centerb[row*3+2];
  {
    const int c = tid;
    float v = cx*pw1[c*3+0] + cy*pw1[c*3+1] + cz*pw1[c*3+2] + pb1[c];
    float u = 0.7978845608028654f * (v + 0.044715f*v*v*v);
    t1[c] = 0.5f*v*(1.0f + tanhf(u));
  }
  __syncthreads();
  float v[3];
  #pragma unroll
  for (int i = 0; i < 3; ++i) {
    int j = tid + i*128;
    float acc = pb2[j];
    const float4* wp = (const float4*)(pw2 + (size_t)j*128);
    const float4* a = (const float4*)t1;
    for (int k4 = 0; k4 < 32; ++k4) {
      float4 wv = wp[k4], av = a[k4];
      acc = fmaf(av.x, wv.x, fmaf(av.y, wv.y, fmaf(av.z, wv.z, fmaf(av.w, wv.w, acc))));
    }
    float r = h[(size_t)row*PDM + j] + acc;
    res[(size_t)row*PDM + j] = r;
    v[i] = r;
  }
  float ss = v[0] + v[1] + v[2];
  #pragma unroll
  for (int off = 1; off < 64; off <<= 1) ss += __shfl_xor(ss, off);
  if ((tid & 63) == 0) s1[tid>>6] = ss;
  __syncthreads();
  const float mu = (s1[0] + s1[1]) * (1.0f/384.0f);
  float qq = 0.f;
  #pragma unroll
  for (int i = 0; i < 3; ++i) { float d = v[i] - mu; qq += d*d; }
  #pragma unroll
  for (int off = 1; off < 64; off <<= 1) qq += __shfl_xor(qq, off);
  if ((tid & 63) == 0) s2[tid>>6] = qq;
  __syncthreads();
  const float rs = rsqrtf((s2[0] + s2[1]) * (1.0f/384.0f) + 1e-5f);
  #pragma unroll
  for (int i = 0; i < 3; ++i) {
    int j = tid + i*128;
    xo[(size_t)row*PDM + j] = f2bf((v[i] - mu) * rs * w[j] + bb[j]);
  }
}

// ---------------------------------------------------------------- prenorm (residual update + LN) -> bf16
__global__ __launch_bounds__(128) void prenorm_kernel(
    const float* __restrict__ h, float* __restrict__ res,
    const float* __restrict__ w, const float* __restrict__ bb,
    ushort_t* __restrict__ xo) {
  const int row = blockIdx.x;
  const int tid = threadIdx.x;
  __shared__ float s1[2], s2[2];
  float v[3];
  #pragma unroll
  for (int i = 0; i < 3; ++i) {
    int j = tid + i*128;
    float r = h[(size_t)row*PDM + j] + res[(size_t)row*PDM + j];
    res[(size_t)row*PDM + j] = r;
    v[i] = r;
  }
  float ss = v[0] + v[1] + v[2];
  #pragma unroll
  for (int off = 1; off < 64; off <<= 1) ss += __shfl_xor(ss, off);
  if ((tid & 63) == 0) s1[tid>>6] = ss;
  __syncthreads();
  const float mu = (s1[0] + s1[1]) * (1.0f/384.0f);
  float qq = 0.f;
  #pragma unroll
  for (int i = 0; i < 3; ++i) { float d = v[i] - mu; qq += d*d; }
  #pragma unroll
  for (int off = 1; off < 64; off <<= 1) qq += __shfl_xor(qq, off);
  if ((tid & 63) == 0) s2[tid>>6] = qq;
  __syncthreads();
  const float rs = rsqrtf((s2[0] + s2[1]) * (1.0f/384.0f) + 1e-5f);
  #pragma unroll
  for (int i = 0; i < 3; ++i) {
    int j = tid + i*128;
    xo[(size_t)row*PDM + j] = f2bf((v[i] - mu) * rs * w[j] + bb[j]);
  }
}

// ---------------------------------------------------------------- final LN -> d_out
__global__ __launch_bounds__(128) void final_kernel(
    const float* __restrict__ h, const float* __restrict__ res,
    const float* __restrict__ w, const float* __restrict__ bb,
    float* __restrict__ out) {
  const int row = blockIdx.x;
  const int tid = threadIdx.x;
  __shared__ float s1[2], s2[2];
  float v[3];
  #pragma unroll
  for (int i = 0; i < 3; ++i) {
    int j = tid + i*128;
    v[i] = h[(size_t)row*PDM + j] + res[(size_t)row*PDM + j];
  }
  float ss = v[0] + v[1] + v[2];
  #pragma unroll
  for (int off = 1; off < 64; off <<= 1) ss += __shfl_xor(ss, off);
  if ((tid & 63) == 0) s1[tid>>6] = ss;
  __syncthreads();
  const float mu = (s1[0] + s1[1]) * (1.0f/384.0f);
  float qq = 0.f;
  #pragma unroll
  for (int i = 0; i < 3; ++i) { float d = v[i] - mu; qq += d*d; }
  #pragma unroll
  for (int off = 1; off < 64; off <<= 1) qq += __shfl_xor(qq, off);
  if ((tid & 63) == 0) s2[tid>>6] = qq;
  __syncthreads();
  const float rs = rsqrtf((s2[0] + s2[1]) * (1.0f/384.0f) + 1e-5f);
  #pragma unroll
  for (int i = 0; i < 3; ++i) {
    int j = tid + i*128;
    out[(size_t)row*PDM + j] = (v[i] - mu) * rs * w[j] + bb[j];
  }
}

// ---------------------------------------------------------------- fused conv+silu + xp (coalesced) + dt
__global__ __launch_bounds__(256) void cxd_kernel(
    const float* __restrict__ xz,
    const float* __restrict__ cw, const float* __restrict__ cb,
    const float* __restrict__ xpwT,
    const float* __restrict__ dtwT, const float* __restrict__ dtbias,
    float* __restrict__ xin, float* __restrict__ dbl, float* __restrict__ dtg) {
  const int row = blockIdx.x;
  const int tid = threadIdx.x;
  const int wid = tid >> 6, lane = tid & 63;
  const int l = row & 127;
  const int bb = row - l;
  __shared__ float xin_s[PDI];
  __shared__ float part[4][64];
  __shared__ float dbl_s[64];
  #pragma unroll
  for (int i = 0; i < 3; ++i) {
    const int d = tid + i*256;
    float acc = cb[d];
    #pragma unroll
    for (int k = 0; k < 4; ++k) {
      int ll = l + k - 3;
      if (ll >= 0) acc = fmaf(xz[(size_t)(bb+ll)*1536 + d], cw[d*4+k], acc);
    }
    float s = 1.0f / (1.0f + __expf(-acc));
    float v = acc * s;
    xin_s[d] = v;
    xin[(size_t)row*PDI + d] = v;
  }
  __syncthreads();
  {
    const float4* wp = (const float4*)xpwT;
    float a = 0.f;
    const int base_r4 = wid*48;
    for (int t = 0; t < 48; ++t) {
      const int r4 = base_r4 + t;
      float4 w4 = wp[r4*64 + lane];
      float4 x4 = *(const float4*)&xin_s[r4*4];
      a = fmaf(x4.x, w4.x, fmaf(x4.y, w4.y, fmaf(x4.z, w4.z, fmaf(x4.w, w4.w, a))));
    }
    part[wid][lane] = a;
  }
  __syncthreads();
  if (tid < 64) {
    float v = part[0][tid] + part[1][tid] + part[2][tid] + part[3][tid];
    dbl_s[tid] = v;
    if (tid < 56) dbl[(size_t)row*56 + tid] = v;
  }
  __syncthreads();
  #pragma unroll
  for (int i = 0; i < 3; ++i) {
    const int d = tid + i*256;
    float acc = dtbias[d];
    #pragma unroll
    for (int r = 0; r < 24; ++r) acc = fmaf(dbl_s[r], dtwT[r*768 + d], acc);
    dtg[(size_t)row*PDI + d] = log1pf(expf(-fabsf(acc))) + fmaxf(acc, 0.0f);
  }
}

// ---------------------------------------------------------------- selective scan + gate -> bf16 (prefetched)
__global__ __launch_bounds__(256) void scan_kernel(const float* __restrict__ dt,
                                                   const float* __restrict__ xin,
                                                   const float* __restrict__ dbl,
                                                   const float* __restrict__ alog,
                                                   const float* __restrict__ dp,
                                                   const float* __restrict__ xz,
                                                   ushort_t* __restrict__ yb) {
  const int s = threadIdx.x & 15;
  const int dl = threadIdx.x >> 4;
  const int d = blockIdx.x*16 + dl;
  const int b = blockIdx.y;
  const float A = -expf(alog[d*16 + s]);
  const float Dv = dp[d];
  float h = 0.f;
  int ro = b*128;
  float dtv = dt[(size_t)ro*PDI + d];
  float xv  = xin[(size_t)ro*PDI + d];
  float Bv  = dbl[(size_t)ro*56 + 24 + s];
  float Cv  = dbl[(size_t)ro*56 + 40 + s];
  float zv  = xz[(size_t)ro*1536 + 768 + d];
  for (int l = 0; l < 128; ++l) {
    float ndt = 0.f, nxv = 0.f, nBv = 0.f, nCv = 0.f, nz = 0.f;
    const int r2 = ro + 1;
    if (l < 127) {
      ndt = dt[(size_t)r2*PDI + d];
      nxv = xin[(size_t)r2*PDI + d];
      nBv = dbl[(size_t)r2*56 + 24 + s];
      nCv = dbl[(size_t)r2*56 + 40 + s];
      nz  = xz[(size_t)r2*1536 + 768 + d];
    }
    float dA = __expf(dtv * A);
    h = fmaf(dA, h, dtv * xv * Bv);
    float p = h * Cv;
    p += __shfl_xor(p, 1);
    p += __shfl_xor(p, 2);
    p += __shfl_xor(p, 4);
    p += __shfl_xor(p, 8);
    if (s == 0) {
      float sg = 1.0f / (1.0f + __expf(-zv));
      yb[(size_t)ro*PDI + d] = f2bf(fmaf(Dv, xv, p) * zv * sg);
    }
    dtv = ndt; xv = nxv; Bv = nBv; Cv = nCv; zv = nz;
    ro = r2;
  }
}

// ---------------------------------------------------------------- host
extern "C" void kernel_launch(void* const* d_in, const int* in_sizes, int n_in,
                              void* d_out, int out_size, void* d_ws, size_t ws_size,
                              hipStream_t stream) {
  const float* xyz    = (const float*)d_in[0];
  const float* e1w1   = (const float*)d_in[1];
  const float* e1b1   = (const float*)d_in[2];
  const float* bn1g   = (const float*)d_in[3];
  const float* bn1b   = (const float*)d_in[4];
  const float* e1w2   = (const float*)d_in[5];
  const float* e1b2   = (const float*)d_in[6];
  const float* e2w1   = (const float*)d_in[7];
  const float* e2b1   = (const float*)d_in[8];
  const float* bn2g   = (const float*)d_in[9];
  const float* bn2b   = (const float*)d_in[10];
  const float* e2w2   = (const float*)d_in[11];
  const float* e2b2   = (const float*)d_in[12];
  const float* pw1    = (const float*)d_in[13];
  const float* pb1    = (const float*)d_in[14];
  const float* pw2    = (const float*)d_in[15];
  const float* pb2    = (const float*)d_in[16];
  const float* in_w   = (const float*)d_in[17];
  const float* conv_w = (const float*)d_in[18];
  const float* conv_b = (const float*)d_in[19];
  const float* xp_w   = (const float*)d_in[20];
  const float* dt_w   = (const float*)d_in[21];
  const float* dt_b   = (const float*)d_in[22];
  const float* A_log  = (const float*)d_in[23];
  const float* Dp     = (const float*)d_in[24];
  const float* out_w  = (const float*)d_in[25];
  const float* lnw    = (const float*)d_in[26];
  const float* lnb    = (const float*)d_in[27];
  const float* fnw    = (const float*)d_in[28];
  const float* fnb    = (const float*)d_in[29];

  char* ws = (char*)d_ws;
  size_t off = 0;
  auto alloc = [&](size_t bytes) { void* p = ws + off; off += (bytes + 255) & ~(size_t)255; return p; };
  int*      cidx    = (int*)     alloc(PB*PG*4);
  float*    centerb = (float*)   alloc(ROWS*3*4);
  float*    nbx     = (float*)   alloc(ROWS*PM*3*4);
  ushort_t* f2b     = (ushort_t*)alloc((size_t)ROWS*PM*256*2);   // 32 MB
  ushort_t* fgb     = (ushort_t*)alloc((size_t)ROWS*256*2);      //  1 MB
  float*    gbuf    = (float*)   alloc((size_t)ROWS*512*4);      //  4 MB
  ushort_t* f3      = (ushort_t*)alloc((size_t)ROWS*PM*512*2);   // 64 MB
  float*    hbuf    = (float*)   alloc((size_t)ROWS*PDM*4);
  float*    resid   = (float*)   alloc((size_t)ROWS*PDM*4);
  ushort_t* xlnb    = (ushort_t*)alloc((size_t)ROWS*PDM*2);
  float*    xz      = (float*)   alloc((size_t)ROWS*1536*4);
  float*    xin     = (float*)   alloc((size_t)ROWS*PDI*4);
  float*    dbl     = (float*)   alloc((size_t)ROWS*56*4);
  float*    dtg     = (float*)   alloc((size_t)ROWS*PDI*4);
  ushort_t* ybufb   = (ushort_t*)alloc((size_t)ROWS*PDI*2);
  ushort_t* wb      = (ushort_t*)alloc((size_t)CV_TOT*2);
  float*    dtwT    = (float*)   alloc((size_t)DTWT_TOT*4);
  float*    xpwT    = (float*)   alloc((size_t)XPWT_TOT*4);

  ushort_t* e1w2b  = wb;
  ushort_t* e2w1b  = wb + CV_O1;
  ushort_t* e2w2b  = wb + CV_O2;
  ushort_t* in_wb  = wb + CV_O3;
  ushort_t* out_wb = wb + CV_O4;

  prep_kernel<<<(PREP_TOT+255)/256, 256, 0, stream>>>(
      e1w2, e2w1, e2w2, in_w, out_w, dt_w, xp_w, wb, dtwT, xpwT);

  fps_kernel<<<PB, 256, 0, stream>>>(xyz, cidx);
  knn_kernel<<<ROWS, 64, 0, stream>>>(xyz, cidx, nbx, centerb);
  embed1_kernel<<<ROWS, 256, 0, stream>>>(nbx, e1w1, e1b1, bn1g, bn1b, e1w2b, e1b2, f2b, fgb);

  // g = fg @ W_left^T  (M=2048, N=512, K=256); W_left = e2w1[:, :256]
  mfma_gemm<2,4,0><<<dim3(4, 32), 256, 0, stream>>>(
      fgb, 256, e2w1b, 512, gbuf, nullptr, 512, 256, nullptr, nullptr, nullptr, nullptr);
  // f3 = relu(bn(f2 @ W_right^T + g[group] + e2b1))  (M=65536, K=256, N=512)
  mfma_gemm<4,4,1><<<dim3(4, 512), 256, 0, stream>>>(
      f2b, 256, e2w1b + 256, 512, nullptr, f3, 512, 256, e2b1, bn2g, bn2b, gbuf);
  // tokens = groupmax(f3 @ e2w2^T) + e2b2  (M=65536, K=512, N=384)
  mfma_gemm<4,4,2><<<dim3(3, 512), 256, 0, stream>>>(
      f3, 512, e2w2b, 512, hbuf, nullptr, PDM, 512, e2b2, nullptr, nullptr, nullptr);

  prenorm0_kernel<<<ROWS, 128, 0, stream>>>(hbuf, centerb, pw1, pb1, pw2, pb2,
                                            resid, lnw, lnb, xlnb);

  for (int i = 0; i < 12; ++i) {
    // in-proj: (2048,384)@(1536,384)^T -> xz
    mfma_gemm<2,4,0><<<dim3(12, 32), 256, 0, stream>>>(
        xlnb, PDM, in_wb + (size_t)i*1536*384, PDM, xz, nullptr, 1536, PDM,
        nullptr, nullptr, nullptr, nullptr);
    cxd_kernel<<<ROWS, 256, 0, stream>>>(
        xz, conv_w + (size_t)i*768*4, conv_b + (size_t)i*768,
        xpwT + (size_t)i*49152, dtwT + (size_t)i*24*768, dt_b + (size_t)i*768,
        xin, dbl, dtg);
    scan_kernel<<<dim3(48, PB), 256, 0, stream>>>(
        dtg, xin, dbl, A_log + (size_t)i*768*16, Dp + (size_t)i*768, xz, ybufb);
    // out-proj: (2048,768)@(384,768)^T -> hbuf
    mfma_gemm<2,2,0><<<dim3(6, 32), 256, 0, stream>>>(
        ybufb, PDI, out_wb + (size_t)i*384*768, PDI, hbuf, nullptr, PDM, PDI,
        nullptr, nullptr, nullptr, nullptr);
    if (i < 11)
      prenorm_kernel<<<ROWS, 128, 0, stream>>>(hbuf, resid, lnw + (i+1)*384, lnb + (i+1)*384, xlnb);
    else
      final_kernel<<<ROWS, 128, 0, stream>>>(hbuf, resid, fnw, fnb, (float*)d_out);
  }
}

// Round 8
// 1543.066 us; speedup vs baseline: 1.4036x; 1.1929x over previous
//
#include <hip/hip_runtime.h>
#include <hip/hip_bf16.h>
#include <math.h>

#define PN   2048
#define PB   16
#define PG   128
#define PM   32
#define PDM  384
#define PDI  768
#define ROWS 2048   // B*G == B*L

typedef unsigned short ushort_t;
typedef unsigned int uint_t;
typedef unsigned long long ull_t;
typedef __attribute__((ext_vector_type(8))) short bf8;
typedef __attribute__((ext_vector_type(4))) float f4;

__device__ __forceinline__ ushort_t f2bf(float x) {
  unsigned int u = __float_as_uint(x);
  unsigned int r = (u + 0x7FFFu + ((u >> 16) & 1u)) >> 16;
  return (ushort_t)r;
}
__device__ __forceinline__ float bf2f(ushort_t u) {
  return __uint_as_float(((unsigned)u) << 16);
}
__device__ __forceinline__ ull_t umax64(ull_t a, ull_t b) { return a > b ? a : b; }
__device__ __forceinline__ ull_t umin64(ull_t a, ull_t b) { return a < b ? a : b; }

// 16-lane (DPP row) sum, result in all 16 lanes. row_ror:1/2/4/8.
__device__ __forceinline__ float rowsum16(float v) {
  v += __int_as_float(__builtin_amdgcn_update_dpp(0, __float_as_int(v), 0x121, 0xF, 0xF, false));
  v += __int_as_float(__builtin_amdgcn_update_dpp(0, __float_as_int(v), 0x122, 0xF, 0xF, false));
  v += __int_as_float(__builtin_amdgcn_update_dpp(0, __float_as_int(v), 0x124, 0xF, 0xF, false));
  v += __int_as_float(__builtin_amdgcn_update_dpp(0, __float_as_int(v), 0x128, 0xF, 0xF, false));
  return v;
}

#define GL2L(gp, lp) __builtin_amdgcn_global_load_lds((const __attribute__((address_space(1))) void*)(gp), (__attribute__((address_space(3))) void*)(lp), 16, 0, 0)

// ---------------------------------------------------------------- prep
#define CV_O1 32768
#define CV_O2 294912
#define CV_O3 491520
#define CV_O4 7569408
#define CV_TOT 11108352
#define DTWT_TOT (12*768*24)
#define XPWT_TOT (12*192*64*4)
#define PREP_TOT (CV_TOT + DTWT_TOT + XPWT_TOT)
__global__ __launch_bounds__(256) void prep_kernel(
    const float* __restrict__ e1w2, const float* __restrict__ e2w1,
    const float* __restrict__ e2w2, const float* __restrict__ in_w,
    const float* __restrict__ out_w, const float* __restrict__ dt_w,
    const float* __restrict__ xp_w,
    ushort_t* __restrict__ wb, float* __restrict__ dtwT,
    float* __restrict__ xpwT) {
  int i = blockIdx.x*256 + threadIdx.x;
  if (i >= PREP_TOT) return;
  if (i < CV_TOT) {
    const float* s; int off;
    if      (i < CV_O1) { s = e1w2;  off = 0; }
    else if (i < CV_O2) { s = e2w1;  off = CV_O1; }
    else if (i < CV_O3) { s = e2w2;  off = CV_O2; }
    else if (i < CV_O4) { s = in_w;  off = CV_O3; }
    else                { s = out_w; off = CV_O4; }
    wb[i] = f2bf(s[i - off]);
  } else if (i < CV_TOT + DTWT_TOT) {
    int j = i - CV_TOT;
    int layer = j / (768*24);
    int rem = j - layer*768*24;
    int d = rem / 24, r = rem - d*24;
    dtwT[layer*24*768 + r*768 + d] = dt_w[j];
  } else {
    int j = i - CV_TOT - DTWT_TOT;
    int layer = j / 49152;
    int rem = j - layer*49152;
    int r4 = rem >> 8;
    int rem2 = rem & 255;
    int e = rem2 >> 2, jj = rem2 & 3;
    xpwT[j] = (e < 56) ? xp_w[(size_t)layer*56*768 + (size_t)e*768 + r4*4 + jj] : 0.f;
  }
}

// ---------------------------------------------------------------- FPS: 4 waves/batch, packed-u64 tree argmax
__global__ __launch_bounds__(256) void fps_kernel(const float* __restrict__ xyz,
                                                  int* __restrict__ cidx) {
  const int b = blockIdx.x;
  const int tid = threadIdx.x;
  const int wave = tid >> 6, lane = tid & 63;
  __shared__ float pts[PN*3];
  __shared__ ull_t kws[2][4];
  const float* base = xyz + (size_t)b * PN * 3;
  for (int t = tid; t < PN*3; t += 256) pts[t] = base[t];
  __syncthreads();
  float px[8], py[8], pz[8], dmin[8];
  #pragma unroll
  for (int j = 0; j < 8; ++j) {
    int idx = j*256 + tid;
    px[j] = pts[idx*3+0]; py[j] = pts[idx*3+1]; pz[j] = pts[idx*3+2];
    dmin[j] = 1e10f;
  }
  int cur = 0;
  for (int g = 0; g < PG; ++g) {
    if (tid == 0) cidx[b*PG + g] = cur;
    const float cx = pts[cur*3+0], cy = pts[cur*3+1], cz = pts[cur*3+2];
    ull_t k[8];
    #pragma unroll
    for (int j = 0; j < 8; ++j) {
      float dx = __fsub_rn(px[j], cx);
      float dy = __fsub_rn(py[j], cy);
      float dz = __fsub_rn(pz[j], cz);
      float dd = __fadd_rn(__fadd_rn(__fmul_rn(dx,dx), __fmul_rn(dy,dy)), __fmul_rn(dz,dz));
      float dm = fminf(dmin[j], dd);
      dmin[j] = dm;
      k[j] = ((ull_t)__float_as_uint(dm) << 32) | (unsigned)(~(unsigned)(j*256 + tid));
    }
    ull_t a0 = umax64(k[0], k[1]), a1 = umax64(k[2], k[3]);
    ull_t a2 = umax64(k[4], k[5]), a3 = umax64(k[6], k[7]);
    ull_t K = umax64(umax64(a0, a1), umax64(a2, a3));
    #pragma unroll
    for (int off = 1; off < 64; off <<= 1)
      K = umax64(K, (ull_t)__shfl_xor((unsigned long long)K, off));
    const int par = g & 1;
    if (lane == 0) kws[par][wave] = K;
    __syncthreads();
    ull_t K0 = umax64(umax64(kws[par][0], kws[par][1]), umax64(kws[par][2], kws[par][3]));
    cur = (int)(~(unsigned)(K0 & 0xFFFFFFFFull));
  }
}

// ---------------------------------------------------------------- kNN: one wave per group, packed-u64 tree argmin
__global__ __launch_bounds__(64) void knn_kernel(const float* __restrict__ xyz,
                                                 const int* __restrict__ cidx,
                                                 float* __restrict__ nbx,
                                                 float* __restrict__ centerb) {
  const int bg = blockIdx.x;
  const int b = bg >> 7;
  const int lane = threadIdx.x;
  const float* base = xyz + (size_t)b * PN * 3;
  const int ci = cidx[bg];
  const float cx = base[ci*3+0], cy = base[ci*3+1], cz = base[ci*3+2];
  if (lane == 0) { centerb[bg*3+0]=cx; centerb[bg*3+1]=cy; centerb[bg*3+2]=cz; }
  float d2[32];
  #pragma unroll
  for (int j = 0; j < 32; ++j) {
    int idx = j*64 + lane;
    float dx = __fsub_rn(cx, base[idx*3+0]);
    float dy = __fsub_rn(cy, base[idx*3+1]);
    float dz = __fsub_rn(cz, base[idx*3+2]);
    d2[j] = __fadd_rn(__fadd_rn(__fmul_rn(dx,dx), __fmul_rn(dy,dy)), __fmul_rn(dz,dz));
  }
  for (int m = 0; m < PM; ++m) {
    ull_t t[16];
    #pragma unroll
    for (int j = 0; j < 16; ++j) {
      ull_t e0 = ((ull_t)__float_as_uint(d2[j])     << 32) | (unsigned)(j*64 + lane);
      ull_t e1 = ((ull_t)__float_as_uint(d2[j+16])  << 32) | (unsigned)((j+16)*64 + lane);
      t[j] = umin64(e0, e1);
    }
    #pragma unroll
    for (int s = 8; s >= 1; s >>= 1)
      #pragma unroll
      for (int j = 0; j < 16; ++j) if (j < s) t[j] = umin64(t[j], t[j+s]);
    ull_t K = t[0];
    #pragma unroll
    for (int off = 1; off < 64; off <<= 1)
      K = umin64(K, (ull_t)__shfl_xor((unsigned long long)K, off));
    const int k = __builtin_amdgcn_readfirstlane((int)(unsigned)(K & 0xFFFFFFFFull));
    const int jwin = k >> 6, owner = k & 63;
    #pragma unroll
    for (int j = 0; j < 32; ++j)
      if (j == jwin && lane == owner) d2[j] = 1e38f;
    if (lane == 0) {
      nbx[(bg*PM + m)*3 + 0] = base[k*3+0] - cx;
      nbx[(bg*PM + m)*3 + 1] = base[k*3+1] - cy;
      nbx[(bg*PM + m)*3 + 2] = base[k*3+2] - cz;
    }
  }
}

// ---------------------------------------------------------------- embed stage A+B -> f2 (bf16 rows) + fg (group max)
__global__ __launch_bounds__(256) void embed1_kernel(
    const float* __restrict__ nbx,
    const float* __restrict__ e1w1, const float* __restrict__ e1b1,
    const float* __restrict__ bn1g, const float* __restrict__ bn1b,
    const ushort_t* __restrict__ e1w2b, const float* __restrict__ e1b2,
    ushort_t* __restrict__ f2b, ushort_t* __restrict__ fgb) {
  const int bg = blockIdx.x;
  const int tid = threadIdx.x;
  const int wid = tid >> 6, lane = tid & 63;
  const int q = lane >> 4, r16 = lane & 15;
  __shared__ float xs[PM*3];
  __shared__ __align__(16) ushort_t Af[4*2*64*8];
  __shared__ __align__(16) ushort_t Bs[16*64*8];
  if (tid < PM*3) xs[tid] = nbx[bg*PM*3 + tid];
  __syncthreads();
  const float bns = rsqrtf(1.0f + 1e-5f);
  #pragma unroll
  for (int it = 0; it < 16; ++it) {
    int id = tid + it*256;
    int m = id >> 7, c = id & 127;
    float v = xs[m*3+0]*e1w1[c*3+0] + xs[m*3+1]*e1w1[c*3+1] + xs[m*3+2]*e1w1[c*3+2] + e1b1[c];
    v = fmaxf(v * (bn1g[c]*bns) + bn1b[c], 0.0f);
    int kc = c >> 5, cc = c & 31, qq = cc >> 3, j = cc & 7;
    int t = m >> 4, r = m & 15;
    Af[((kc*2 + t)*64 + qq*16 + r)*8 + j] = f2bf(v);
  }
  f4 acc[2][4];
  #pragma unroll
  for (int t = 0; t < 2; ++t)
    #pragma unroll
    for (int jj = 0; jj < 4; ++jj) { f4 z = {0.f,0.f,0.f,0.f}; acc[t][jj] = z; }
  for (int kc = 0; kc < 4; ++kc) {
    #pragma unroll
    for (int u = wid; u < 16; u += 4)
      GL2L(e1w2b + (size_t)(u*16 + r16)*128 + kc*32 + q*8, Bs + u*512);
    __syncthreads();
    bf8 a0 = *(const bf8*)(Af + ((size_t)((kc*2+0)*64 + lane))*8);
    bf8 a1 = *(const bf8*)(Af + ((size_t)((kc*2+1)*64 + lane))*8);
    #pragma unroll
    for (int jj = 0; jj < 4; ++jj) {
      bf8 bv = *(const bf8*)(Bs + ((size_t)((wid*4+jj)*64 + lane))*8);
      acc[0][jj] = __builtin_amdgcn_mfma_f32_16x16x32_bf16(a0, bv, acc[0][jj], 0, 0, 0);
      acc[1][jj] = __builtin_amdgcn_mfma_f32_16x16x32_bf16(a1, bv, acc[1][jj], 0, 0, 0);
    }
    __syncthreads();
  }
  #pragma unroll
  for (int jj = 0; jj < 4; ++jj) {
    const int n = (wid*4+jj)*16 + r16;
    const float bias = e1b2[n];
    float v0[4], v1[4];
    float cm = -1e30f;
    #pragma unroll
    for (int rr = 0; rr < 4; ++rr) {
      v0[rr] = acc[0][jj][rr] + bias;
      v1[rr] = acc[1][jj][rr] + bias;
      cm = fmaxf(cm, fmaxf(v0[rr], v1[rr]));
    }
    cm = fmaxf(cm, __shfl_xor(cm, 16));
    cm = fmaxf(cm, __shfl_xor(cm, 32));
    #pragma unroll
    for (int rr = 0; rr < 4; ++rr) {
      f2b[((size_t)bg*32 + q*4 + rr)*256 + n]      = f2bf(v0[rr]);
      f2b[((size_t)bg*32 + 16 + q*4 + rr)*256 + n] = f2bf(v1[rr]);
    }
    if (lane < 16) fgb[(size_t)bg*256 + n] = f2bf(cm);
  }
}

// ---------------------------------------------------------------- bf16 MFMA GEMM, BK=64
// EPI 0: fp32 store. EPI 1: relu(bn(acc + p3[group] + p0)) -> bf16 (gemmC').
// EPI 2: group(32-row) max + p0 -> fp32 tokens (MT=4). EPI 3: bf16 store.
template<int MT, int NT, int EPI>
__global__ __launch_bounds__(256) void mfma_gemm(
    const ushort_t* __restrict__ A, int lda,
    const ushort_t* __restrict__ W, int ldw,
    float* __restrict__ Cf, ushort_t* __restrict__ Cb, int ldc, int K,
    const float* __restrict__ p0, const float* __restrict__ p1,
    const float* __restrict__ p2, const float* __restrict__ p3) {
  static_assert(EPI != 2 || MT == 4, "groupmax needs MT=4");
  constexpr int AT = 2*MT, BT = 2*NT;
  __shared__ __align__(16) ushort_t As[2*AT*512];
  __shared__ __align__(16) ushort_t Bs[2*BT*512];
  const int tid = threadIdx.x;
  const int wid = tid >> 6, lane = tid & 63;
  const int wr = wid >> 1, wc = wid & 1;
  const int q = lane >> 4, r16 = lane & 15;
  const int m0 = blockIdx.y * (32*MT);
  const int n0 = blockIdx.x * (32*NT);
  f4 acc[MT][NT];
  #pragma unroll
  for (int i = 0; i < MT; ++i)
    #pragma unroll
    for (int j = 0; j < NT; ++j) { f4 z = {0.f,0.f,0.f,0.f}; acc[i][j] = z; }

  for (int k0 = 0; k0 < K; k0 += 64) {
    #pragma unroll
    for (int c = 0; c < 2; ++c) {
      const int kk = k0 + c*32 + q*8;
      #pragma unroll
      for (int t = wid; t < AT; t += 4)
        GL2L(A + (size_t)(m0 + t*16 + r16)*lda + kk, As + (c*AT + t)*512);
      #pragma unroll
      for (int t = wid; t < BT; t += 4)
        GL2L(W + (size_t)(n0 + t*16 + r16)*ldw + kk, Bs + (c*BT + t)*512);
    }
    __syncthreads();
    #pragma unroll
    for (int c = 0; c < 2; ++c) {
      bf8 af[MT], bfr[NT];
      #pragma unroll
      for (int i = 0; i < MT; ++i)
        af[i] = *(const bf8*)(As + ((size_t)(c*AT + wr*MT+i)*64 + lane)*8);
      #pragma unroll
      for (int j = 0; j < NT; ++j)
        bfr[j] = *(const bf8*)(Bs + ((size_t)(c*BT + wc*NT+j)*64 + lane)*8);
      #pragma unroll
      for (int i = 0; i < MT; ++i)
        #pragma unroll
        for (int j = 0; j < NT; ++j)
          acc[i][j] = __builtin_amdgcn_mfma_f32_16x16x32_bf16(af[i], bfr[j], acc[i][j], 0, 0, 0);
    }
    __syncthreads();
  }

  if constexpr (EPI == 0) {
    #pragma unroll
    for (int i = 0; i < MT; ++i) {
      const int row = m0 + (wr*MT+i)*16 + q*4;
      #pragma unroll
      for (int j = 0; j < NT; ++j) {
        const int col = n0 + (wc*NT+j)*16 + r16;
        #pragma unroll
        for (int r = 0; r < 4; ++r)
          Cf[(size_t)(row+r)*ldc + col] = acc[i][j][r];
      }
    }
  } else if constexpr (EPI == 1) {
    const float bns = rsqrtf(1.0f + 1e-5f);
    #pragma unroll
    for (int j = 0; j < NT; ++j) {
      const int col = n0 + (wc*NT+j)*16 + r16;
      const float b1 = p0[col], sg = p1[col]*bns, b2 = p2[col];
      #pragma unroll
      for (int i = 0; i < MT; ++i) {
        const int row = m0 + (wr*MT+i)*16 + q*4;
        #pragma unroll
        for (int r = 0; r < 4; ++r) {
          const int grp = (row + r) >> 5;
          float v = fmaxf(fmaf(acc[i][j][r] + b1 + p3[(size_t)grp*512 + col], sg, b2), 0.0f);
          Cb[(size_t)(row+r)*ldc + col] = f2bf(v);
        }
      }
    }
  } else if constexpr (EPI == 3) {
    #pragma unroll
    for (int i = 0; i < MT; ++i) {
      const int row = m0 + (wr*MT+i)*16 + q*4;
      #pragma unroll
      for (int j = 0; j < NT; ++j) {
        const int col = n0 + (wc*NT+j)*16 + r16;
        #pragma unroll
        for (int r = 0; r < 4; ++r)
          Cb[(size_t)(row+r)*ldc + col] = f2bf(acc[i][j][r]);
      }
    }
  } else {
    #pragma unroll
    for (int j = 0; j < NT; ++j) {
      const int col = n0 + (wc*NT+j)*16 + r16;
      float tm[4];
      #pragma unroll
      for (int i = 0; i < 4; ++i) {
        float t = fmaxf(fmaxf(acc[i][j][0], acc[i][j][1]), fmaxf(acc[i][j][2], acc[i][j][3]));
        t = fmaxf(t, __shfl_xor(t, 16));
        t = fmaxf(t, __shfl_xor(t, 32));
        tm[i] = t;
      }
      const float bias = p0[col];
      if (lane < 16) {
        const int g0 = (m0 >> 5) + wr*2;
        Cf[(size_t)g0*ldc + col]     = fmaxf(tm[0], tm[1]) + bias;
        Cf[(size_t)(g0+1)*ldc + col] = fmaxf(tm[2], tm[3]) + bias;
      }
    }
  }
}

// ---------------------------------------------------------------- prenorm0: pos-MLP + resid init + LN -> bf16
__global__ __launch_bounds__(128) void prenorm0_kernel(
    const float* __restrict__ h, const float* __restrict__ centerb,
    const float* __restrict__ pw1, const float* __restrict__ pb1,
    const float* __restrict__ pw2, const float* __restrict__ pb2,
    float* __restrict__ res,
    const float* __restrict__ w, const float* __restrict__ bb,
    ushort_t* __restrict__ xo) {
  const int row = blockIdx.x;
  const int tid = threadIdx.x;
  __shared__ float t1[128];
  __shared__ float s1[2], s2[2];
  const float cx = centerb[row*3+0], cy = centerb[row*3+1], cz = centerb[row*3+2];
  {
    const int c = tid;
    float v = cx*pw1[c*3+0] + cy*pw1[c*3+1] + cz*pw1[c*3+2] + pb1[c];
    float u = 0.7978845608028654f * (v + 0.044715f*v*v*v);
    t1[c] = 0.5f*v*(1.0f + tanhf(u));
  }
  __syncthreads();
  float v[3];
  #pragma unroll
  for (int i = 0; i < 3; ++i) {
    int j = tid + i*128;
    float acc = pb2[j];
    const float4* wp = (const float4*)(pw2 + (size_t)j*128);
    const float4* a = (const float4*)t1;
    for (int k4 = 0; k4 < 32; ++k4) {
      float4 wv = wp[k4], av = a[k4];
      acc = fmaf(av.x, wv.x, fmaf(av.y, wv.y, fmaf(av.z, wv.z, fmaf(av.w, wv.w, acc))));
    }
    float r = h[(size_t)row*PDM + j] + acc;
    res[(size_t)row*PDM + j] = r;
    v[i] = r;
  }
  float ss = v[0] + v[1] + v[2];
  #pragma unroll
  for (int off = 1; off < 64; off <<= 1) ss += __shfl_xor(ss, off);
  if ((tid & 63) == 0) s1[tid>>6] = ss;
  __syncthreads();
  const float mu = (s1[0] + s1[1]) * (1.0f/384.0f);
  float qq = 0.f;
  #pragma unroll
  for (int i = 0; i < 3; ++i) { float d = v[i] - mu; qq += d*d; }
  #pragma unroll
  for (int off = 1; off < 64; off <<= 1) qq += __shfl_xor(qq, off);
  if ((tid & 63) == 0) s2[tid>>6] = qq;
  __syncthreads();
  const float rs = rsqrtf((s2[0] + s2[1]) * (1.0f/384.0f) + 1e-5f);
  #pragma unroll
  for (int i = 0; i < 3; ++i) {
    int j = tid + i*128;
    xo[(size_t)row*PDM + j] = f2bf((v[i] - mu) * rs * w[j] + bb[j]);
  }
}

// ---------------------------------------------------------------- prenorm (residual update + LN) -> bf16
__global__ __launch_bounds__(128) void prenorm_kernel(
    const float* __restrict__ h, float* __restrict__ res,
    const float* __restrict__ w, const float* __restrict__ bb,
    ushort_t* __restrict__ xo) {
  const int row = blockIdx.x;
  const int tid = threadIdx.x;
  __shared__ float s1[2], s2[2];
  float v[3];
  #pragma unroll
  for (int i = 0; i < 3; ++i) {
    int j = tid + i*128;
    float r = h[(size_t)row*PDM + j] + res[(size_t)row*PDM + j];
    res[(size_t)row*PDM + j] = r;
    v[i] = r;
  }
  float ss = v[0] + v[1] + v[2];
  #pragma unroll
  for (int off = 1; off < 64; off <<= 1) ss += __shfl_xor(ss, off);
  if ((tid & 63) == 0) s1[tid>>6] = ss;
  __syncthreads();
  const float mu = (s1[0] + s1[1]) * (1.0f/384.0f);
  float qq = 0.f;
  #pragma unroll
  for (int i = 0; i < 3; ++i) { float d = v[i] - mu; qq += d*d; }
  #pragma unroll
  for (int off = 1; off < 64; off <<= 1) qq += __shfl_xor(qq, off);
  if ((tid & 63) == 0) s2[tid>>6] = qq;
  __syncthreads();
  const float rs = rsqrtf((s2[0] + s2[1]) * (1.0f/384.0f) + 1e-5f);
  #pragma unroll
  for (int i = 0; i < 3; ++i) {
    int j = tid + i*128;
    xo[(size_t)row*PDM + j] = f2bf((v[i] - mu) * rs * w[j] + bb[j]);
  }
}

// ---------------------------------------------------------------- final LN -> d_out
__global__ __launch_bounds__(128) void final_kernel(
    const float* __restrict__ h, const float* __restrict__ res,
    const float* __restrict__ w, const float* __restrict__ bb,
    float* __restrict__ out) {
  const int row = blockIdx.x;
  const int tid = threadIdx.x;
  __shared__ float s1[2], s2[2];
  float v[3];
  #pragma unroll
  for (int i = 0; i < 3; ++i) {
    int j = tid + i*128;
    v[i] = h[(size_t)row*PDM + j] + res[(size_t)row*PDM + j];
  }
  float ss = v[0] + v[1] + v[2];
  #pragma unroll
  for (int off = 1; off < 64; off <<= 1) ss += __shfl_xor(ss, off);
  if ((tid & 63) == 0) s1[tid>>6] = ss;
  __syncthreads();
  const float mu = (s1[0] + s1[1]) * (1.0f/384.0f);
  float qq = 0.f;
  #pragma unroll
  for (int i = 0; i < 3; ++i) { float d = v[i] - mu; qq += d*d; }
  #pragma unroll
  for (int off = 1; off < 64; off <<= 1) qq += __shfl_xor(qq, off);
  if ((tid & 63) == 0) s2[tid>>6] = qq;
  __syncthreads();
  const float rs = rsqrtf((s2[0] + s2[1]) * (1.0f/384.0f) + 1e-5f);
  #pragma unroll
  for (int i = 0; i < 3; ++i) {
    int j = tid + i*128;
    out[(size_t)row*PDM + j] = (v[i] - mu) * rs * w[j] + bb[j];
  }
}

// ---------------------------------------------------------------- fused conv+silu + xp (bf16 in/out, no dt)
__global__ __launch_bounds__(256) void cxd_kernel(
    const ushort_t* __restrict__ xzb,
    const float* __restrict__ cw, const float* __restrict__ cb,
    const float* __restrict__ xpwT,
    ushort_t* __restrict__ xinb, float* __restrict__ dbl) {
  const int row = blockIdx.x;
  const int tid = threadIdx.x;
  const int wid = tid >> 6, lane = tid & 63;
  const int l = row & 127;
  const int bb = row - l;
  __shared__ float xin_s[PDI];
  __shared__ float part[4][64];
  #pragma unroll
  for (int i = 0; i < 3; ++i) {
    const int d = tid + i*256;
    float acc = cb[d];
    #pragma unroll
    for (int k = 0; k < 4; ++k) {
      int ll = l + k - 3;
      if (ll >= 0) acc = fmaf(bf2f(xzb[(size_t)(bb+ll)*1536 + d]), cw[d*4+k], acc);
    }
    float s = 1.0f / (1.0f + __expf(-acc));
    float v = acc * s;
    xin_s[d] = v;
    xinb[(size_t)row*PDI + d] = f2bf(v);
  }
  __syncthreads();
  {
    const float4* wp = (const float4*)xpwT;
    float a = 0.f;
    const int base_r4 = wid*48;
    for (int t = 0; t < 48; ++t) {
      const int r4 = base_r4 + t;
      float4 w4 = wp[r4*64 + lane];
      float4 x4 = *(const float4*)&xin_s[r4*4];
      a = fmaf(x4.x, w4.x, fmaf(x4.y, w4.y, fmaf(x4.z, w4.z, fmaf(x4.w, w4.w, a))));
    }
    part[wid][lane] = a;
  }
  __syncthreads();
  if (tid < 64) {
    float v = part[0][tid] + part[1][tid] + part[2][tid] + part[3][tid];
    if (tid < 56) dbl[(size_t)row*56 + tid] = v;
  }
}

// ---------------------------------------------------------------- scan: LDS-resident, fused dt, DPP reduce, fused gate
// block = (16 channels, 1 batch); grid (48, 16)
__global__ __launch_bounds__(256) void scan_kernel(
    const ushort_t* __restrict__ xzb,
    const ushort_t* __restrict__ xinb,
    const float* __restrict__ dbl,
    const float* __restrict__ dtwT, const float* __restrict__ dtbias,
    const float* __restrict__ alog, const float* __restrict__ dp,
    ushort_t* __restrict__ yb) {
  const int d0 = blockIdx.x * 16;
  const int b  = blockIdx.y;
  const int tid = threadIdx.x;
  __shared__ float dbl_s[128*56];     // 28 KB
  __shared__ float dts[128*16];       //  8 KB
  __shared__ float dtw_s[24*16];      //  1.5 KB
  __shared__ ushort_t xins[128*16];   //  4 KB
  __shared__ ushort_t zs[128*16];     //  4 KB
  __shared__ ushort_t ys[128*16];     //  4 KB
  {
    const float4* src = (const float4*)(dbl + (size_t)b*128*56);
    float4* dst = (float4*)dbl_s;
    for (int i = tid; i < 1792; i += 256) dst[i] = src[i];
  }
  for (int i = tid; i < 24*16; i += 256) {
    int r = i >> 4, c = i & 15;
    dtw_s[i] = dtwT[r*768 + d0 + c];
  }
  for (int i = tid; i < 1024; i += 256) {
    int l = i >> 3, c2 = (i & 7)*2;
    *(uint_t*)&xins[l*16 + c2] = *(const uint_t*)(xinb + ((size_t)(b*128 + l))*768 + d0 + c2);
    *(uint_t*)&zs[l*16 + c2]   = *(const uint_t*)(xzb + ((size_t)(b*128 + l))*1536 + 768 + d0 + c2);
  }
  __syncthreads();
  for (int i = tid; i < 2048; i += 256) {
    int l = i >> 4, c = i & 15;
    float acc = dtbias[d0 + c];
    #pragma unroll
    for (int r = 0; r < 24; ++r) acc = fmaf(dbl_s[l*56 + r], dtw_s[r*16 + c], acc);
    dts[i] = log1pf(expf(-fabsf(acc))) + fmaxf(acc, 0.0f);
  }
  __syncthreads();
  const int s = tid & 15, dl = tid >> 4;
  const int d = d0 + dl;
  const float A = -expf(alog[d*16 + s]);
  const float Dv = dp[d];
  float h = 0.f;
  #pragma unroll 4
  for (int l = 0; l < 128; ++l) {
    float dtv = dts[l*16 + dl];
    float xv  = bf2f(xins[l*16 + dl]);
    float Bv  = dbl_s[l*56 + 24 + s];
    float Cv  = dbl_s[l*56 + 40 + s];
    float dA = __expf(dtv * A);
    h = fmaf(dA, h, dtv * xv * Bv);
    float p = rowsum16(h * Cv);
    if (s == 0) {
      float z = bf2f(zs[l*16 + dl]);
      float sg = 1.0f / (1.0f + __expf(-z));
      ys[l*16 + dl] = f2bf(fmaf(Dv, xv, p) * z * sg);
    }
  }
  __syncthreads();
  for (int i = tid; i < 1024; i += 256) {
    int l = i >> 3, c2 = (i & 7)*2;
    *(uint_t*)(yb + ((size_t)(b*128 + l))*768 + d0 + c2) = *(const uint_t*)&ys[l*16 + c2];
  }
}

// ---------------------------------------------------------------- host
extern "C" void kernel_launch(void* const* d_in, const int* in_sizes, int n_in,
                              void* d_out, int out_size, void* d_ws, size_t ws_size,
                              hipStream_t stream) {
  const float* xyz    = (const float*)d_in[0];
  const float* e1w1   = (const float*)d_in[1];
  const float* e1b1   = (const float*)d_in[2];
  const float* bn1g   = (const float*)d_in[3];
  const float* bn1b   = (const float*)d_in[4];
  const float* e1w2   = (const float*)d_in[5];
  const float* e1b2   = (const float*)d_in[6];
  const float* e2w1   = (const float*)d_in[7];
  const float* e2b1   = (const float*)d_in[8];
  const float* bn2g   = (const float*)d_in[9];
  const float* bn2b   = (const float*)d_in[10];
  const float* e2w2   = (const float*)d_in[11];
  const float* e2b2   = (const float*)d_in[12];
  const float* pw1    = (const float*)d_in[13];
  const float* pb1    = (const float*)d_in[14];
  const float* pw2    = (const float*)d_in[15];
  const float* pb2    = (const float*)d_in[16];
  const float* in_w   = (const float*)d_in[17];
  const float* conv_w = (const float*)d_in[18];
  const float* conv_b = (const float*)d_in[19];
  const float* xp_w   = (const float*)d_in[20];
  const float* dt_w   = (const float*)d_in[21];
  const float* dt_b   = (const float*)d_in[22];
  const float* A_log  = (const float*)d_in[23];
  const float* Dp     = (const float*)d_in[24];
  const float* out_w  = (const float*)d_in[25];
  const float* lnw    = (const float*)d_in[26];
  const float* lnb    = (const float*)d_in[27];
  const float* fnw    = (const float*)d_in[28];
  const float* fnb    = (const float*)d_in[29];

  char* ws = (char*)d_ws;
  size_t off = 0;
  auto alloc = [&](size_t bytes) { void* p = ws + off; off += (bytes + 255) & ~(size_t)255; return p; };
  int*      cidx    = (int*)     alloc(PB*PG*4);
  float*    centerb = (float*)   alloc(ROWS*3*4);
  float*    nbx     = (float*)   alloc(ROWS*PM*3*4);
  ushort_t* f2b     = (ushort_t*)alloc((size_t)ROWS*PM*256*2);   // 32 MB
  ushort_t* fgb     = (ushort_t*)alloc((size_t)ROWS*256*2);      //  1 MB
  float*    gbuf    = (float*)   alloc((size_t)ROWS*512*4);      //  4 MB
  ushort_t* f3      = (ushort_t*)alloc((size_t)ROWS*PM*512*2);   // 64 MB
  float*    hbuf    = (float*)   alloc((size_t)ROWS*PDM*4);
  float*    resid   = (float*)   alloc((size_t)ROWS*PDM*4);
  ushort_t* xlnb    = (ushort_t*)alloc((size_t)ROWS*PDM*2);
  ushort_t* xzb     = (ushort_t*)alloc((size_t)ROWS*1536*2);
  ushort_t* xinb    = (ushort_t*)alloc((size_t)ROWS*PDI*2);
  float*    dbl     = (float*)   alloc((size_t)ROWS*56*4);
  ushort_t* ybufb   = (ushort_t*)alloc((size_t)ROWS*PDI*2);
  ushort_t* wb      = (ushort_t*)alloc((size_t)CV_TOT*2);
  float*    dtwT    = (float*)   alloc((size_t)DTWT_TOT*4);
  float*    xpwT    = (float*)   alloc((size_t)XPWT_TOT*4);

  ushort_t* e1w2b  = wb;
  ushort_t* e2w1b  = wb + CV_O1;
  ushort_t* e2w2b  = wb + CV_O2;
  ushort_t* in_wb  = wb + CV_O3;
  ushort_t* out_wb = wb + CV_O4;

  prep_kernel<<<(PREP_TOT+255)/256, 256, 0, stream>>>(
      e1w2, e2w1, e2w2, in_w, out_w, dt_w, xp_w, wb, dtwT, xpwT);

  fps_kernel<<<PB, 256, 0, stream>>>(xyz, cidx);
  knn_kernel<<<ROWS, 64, 0, stream>>>(xyz, cidx, nbx, centerb);
  embed1_kernel<<<ROWS, 256, 0, stream>>>(nbx, e1w1, e1b1, bn1g, bn1b, e1w2b, e1b2, f2b, fgb);

  // g = fg @ W_left^T  (M=2048, N=512, K=256)
  mfma_gemm<2,4,0><<<dim3(4, 32), 256, 0, stream>>>(
      fgb, 256, e2w1b, 512, gbuf, nullptr, 512, 256, nullptr, nullptr, nullptr, nullptr);
  // f3 = relu(bn(f2 @ W_right^T + g[group] + e2b1))
  mfma_gemm<4,4,1><<<dim3(4, 512), 256, 0, stream>>>(
      f2b, 256, e2w1b + 256, 512, nullptr, f3, 512, 256, e2b1, bn2g, bn2b, gbuf);
  // tokens = groupmax(f3 @ e2w2^T) + e2b2
  mfma_gemm<4,4,2><<<dim3(3, 512), 256, 0, stream>>>(
      f3, 512, e2w2b, 512, hbuf, nullptr, PDM, 512, e2b2, nullptr, nullptr, nullptr);

  prenorm0_kernel<<<ROWS, 128, 0, stream>>>(hbuf, centerb, pw1, pb1, pw2, pb2,
                                            resid, lnw, lnb, xlnb);

  for (int i = 0; i < 12; ++i) {
    // in-proj: (2048,384)@(1536,384)^T -> xzb (bf16)
    mfma_gemm<2,4,3><<<dim3(12, 32), 256, 0, stream>>>(
        xlnb, PDM, in_wb + (size_t)i*1536*384, PDM, nullptr, xzb, 1536, PDM,
        nullptr, nullptr, nullptr, nullptr);
    cxd_kernel<<<ROWS, 256, 0, stream>>>(
        xzb, conv_w + (size_t)i*768*4, conv_b + (size_t)i*768,
        xpwT + (size_t)i*49152, xinb, dbl);
    scan_kernel<<<dim3(48, PB), 256, 0, stream>>>(
        xzb, xinb, dbl, dtwT + (size_t)i*24*768, dt_b + (size_t)i*768,
        A_log + (size_t)i*768*16, Dp + (size_t)i*768, ybufb);
    // out-proj: (2048,768)@(384,768)^T -> hbuf
    mfma_gemm<2,2,0><<<dim3(6, 32), 256, 0, stream>>>(
        ybufb, PDI, out_wb + (size_t)i*384*768, PDI, hbuf, nullptr, PDM, PDI,
        nullptr, nullptr, nullptr, nullptr);
    if (i < 11)
      prenorm_kernel<<<ROWS, 128, 0, stream>>>(hbuf, resid, lnw + (i+1)*384, lnb + (i+1)*384, xlnb);
    else
      final_kernel<<<ROWS, 128, 0, stream>>>(hbuf, resid, fnw, fnb, (float*)d_out);
  }
}